// Round 20
// baseline (124.773 us; speedup 1.0000x reference)
//
#include <hip/hip_runtime.h>

#define DM 1024
#define BATCH 4
#define SEQ 2048
#define M_TOT (BATCH*SEQ)

typedef unsigned short ushort_t;
typedef __bf16 bf16x8 __attribute__((ext_vector_type(8)));
typedef float f32x4 __attribute__((ext_vector_type(4)));
typedef unsigned short u16x4 __attribute__((ext_vector_type(4)));
typedef unsigned short u16x8 __attribute__((ext_vector_type(8)));

__device__ __forceinline__ ushort_t f2bf(float f) {
  unsigned u = __builtin_bit_cast(unsigned, f);
  u = (u + 0x7fffu + ((u >> 16) & 1u)) >> 16;
  return (ushort_t)u;
}
__device__ __forceinline__ float bf2f(ushort_t h) {
  unsigned u = ((unsigned)h) << 16;
  return __builtin_bit_cast(float, u);
}

// async global->LDS, 16B per lane, wave-uniform LDS base + lane*16
#define GLL(gp, lp)                                                            \
  __builtin_amdgcn_global_load_lds(                                            \
      (const __attribute__((address_space(1))) unsigned int*)(const void*)(gp),\
      (__attribute__((address_space(3))) unsigned int*)(void*)(lp), 16, 0, 0)

// ---------------------------------------------------------------------------
// K1 (ATOMIC-FREE): per-block partial sums over 16 rows, coalesced f4 stores;
// qb = bf16(gqw*q), vb = bf16(v). grid (BATCH, SEQ/16), block 256.
__global__ void k_reduce(const float* __restrict__ q, const float* __restrict__ k,
                         const float* __restrict__ v,
                         const float* __restrict__ gqw, const float* __restrict__ gkw,
                         float* __restrict__ pq, float* __restrict__ pk,
                         float* __restrict__ G,
                         ushort_t* __restrict__ qb, ushort_t* __restrict__ vb) {
  const int b = blockIdx.x, sc = blockIdx.y;   // sc: 0..127 (16-row chunks)
  const int d0 = threadIdx.x * 4;
  const int s0 = sc * 16;
  const size_t base = ((size_t)b * SEQ + s0) * DM + d0;
  float aq0 = 0.f, aq1 = 0.f, aq2 = 0.f, aq3 = 0.f;
  float ak0 = 0.f, ak1 = 0.f, ak2 = 0.f, ak3 = 0.f;
  float sgq = 0.f, sgk = 0.f;
#pragma unroll 4
  for (int i = 0; i < 16; ++i) {
    const float wq_ = gqw[s0 + i], wk_ = gkw[s0 + i];
    const size_t off = base + (size_t)i * DM;
    const float4 qv = *(const float4*)(q + off);
    const float4 kv = *(const float4*)(k + off);
    const float4 vv = *(const float4*)(v + off);
    aq0 += wq_ * qv.x; aq1 += wq_ * qv.y; aq2 += wq_ * qv.z; aq3 += wq_ * qv.w;
    ak0 += wk_ * kv.x; ak1 += wk_ * kv.y; ak2 += wk_ * kv.z; ak3 += wk_ * kv.w;
    u16x4 oq, ov;
    oq[0] = f2bf(wq_ * qv.x); oq[1] = f2bf(wq_ * qv.y);
    oq[2] = f2bf(wq_ * qv.z); oq[3] = f2bf(wq_ * qv.w);
    ov[0] = f2bf(vv.x); ov[1] = f2bf(vv.y); ov[2] = f2bf(vv.z); ov[3] = f2bf(vv.w);
    *(u16x4*)(qb + off) = oq;
    *(u16x4*)(vb + off) = ov;
    sgq += wq_; sgk += wk_;
  }
  const size_t po = ((size_t)(sc * BATCH + b) << 10) + d0;
  *(float4*)(pq + po) = make_float4(aq0, aq1, aq2, aq3);
  *(float4*)(pk + po) = make_float4(ak0, ak1, ak2, ak3);
  if (b == 0 && threadIdx.x == 0) {
    atomicAdd(&G[0], sgq);
    atomicAdd(&G[1], sgk);
  }
}

// K2: GEMV partials with INLINE partial-fold (k_rsum eliminated).
// First 128 threads reduce 128 slots of pq/pk (L2-resident) for their (b,kk);
// then all 256 threads do the 32-deep dot for their column d.
__global__ void k_gpart(const float* __restrict__ wq, const float* __restrict__ wk,
                        const float* __restrict__ pq, const float* __restrict__ pk,
                        float* __restrict__ qacc, float* __restrict__ kacc) {
  const int d = blockIdx.x * 256 + threadIdx.x;
  const int k0 = blockIdx.y * 32;
  __shared__ float sq[4][32], sk[4][32];
  if (threadIdx.x < 128) {
    const int b = threadIdx.x >> 5, kk = threadIdx.x & 31;
    float aq = 0.f, ak = 0.f;
#pragma unroll 4
    for (int s = 0; s < 128; ++s) {
      const size_t po = ((size_t)(s * BATCH + b) << 10) + k0 + kk;
      aq += pq[po];
      ak += pk[po];
    }
    sq[b][kk] = aq;
    sk[b][kk] = ak;
  }
  __syncthreads();
  float aq[4] = {0.f, 0.f, 0.f, 0.f}, ak[4] = {0.f, 0.f, 0.f, 0.f};
#pragma unroll 8
  for (int kk = 0; kk < 32; ++kk) {
    const float wqv = wq[(size_t)(k0 + kk) * DM + d];
    const float wkv = wk[(size_t)(k0 + kk) * DM + d];
#pragma unroll
    for (int b = 0; b < 4; ++b) {
      aq[b] += sq[b][kk] * wqv;
      ak[b] += sk[b][kk] * wkv;
    }
  }
#pragma unroll
  for (int b = 0; b < 4; ++b) {
    atomicAdd(&qacc[b * DM + d], aq[b]);
    atomicAdd(&kacc[b * DM + d], ak[b]);
  }
}

// K3: merged weight prep. 1D grid 2048: [0,512) conv wq->wqB; [512,1024)
// conv wv->wvB; [1024,2048) transpose-convert wo->woT.
__global__ void k_wprep(const float* __restrict__ wq, const float* __restrict__ wv,
                        const float* __restrict__ wo,
                        ushort_t* __restrict__ wqB, ushort_t* __restrict__ wvB,
                        ushort_t* __restrict__ woT) {
  const int bid = blockIdx.x;
  if (bid < 1024) {
    const float* x = bid < 512 ? wq : wv;
    ushort_t* y = bid < 512 ? wqB : wvB;
    size_t i = (size_t)(bid & 511) * 256 + threadIdx.x;
    const float4* p = (const float4*)x + i * 2;
    float4 a = p[0], bb = p[1];
    u16x8 o;
    o[0] = f2bf(a.x); o[1] = f2bf(a.y); o[2] = f2bf(a.z); o[3] = f2bf(a.w);
    o[4] = f2bf(bb.x); o[5] = f2bf(bb.y); o[6] = f2bf(bb.z); o[7] = f2bf(bb.w);
    *(u16x8*)(y + i * 8) = o;
  } else {
    __shared__ float ls[32][33];
    const int t = bid - 1024;
    const int bi = t >> 5, bj = t & 31;
#pragma unroll
    for (int p = 0; p < 4; ++p) {
      int e = threadIdx.x + p * 256;
      int r = e >> 5, c = e & 31;
      ls[r][c] = wo[(size_t)(bi * 32 + r) * DM + bj * 32 + c];
    }
    __syncthreads();
#pragma unroll
    for (int p = 0; p < 4; ++p) {
      int e = threadIdx.x + p * 256;
      int r = e >> 5, c = e & 31;
      woT[(size_t)(bj * 32 + r) * DM + bi * 32 + c] = f2bf(ls[c][r]);
    }
  }
}

// K4: merged wog + bias (1D grid 2176; branch at 2048). gk inline.
// [0,2048):  wogT[b][n][j] = woT[n][j] * gk[b][j]
// [2048,2176): qbias[n] += sum_j bq[j]*wo[j,n]; vbias[b][n] += ... gk inline.
__global__ void k_wogbias(const ushort_t* __restrict__ woT, const float* __restrict__ wo,
                          const float* __restrict__ qacc, const float* __restrict__ kacc,
                          const float* __restrict__ bq, const float* __restrict__ bk,
                          const float* __restrict__ bv, const float* __restrict__ G,
                          ushort_t* __restrict__ wogT,
                          float* __restrict__ qbias, float* __restrict__ vbias) {
  const int bid = blockIdx.x;
  const float G0 = G[0], G1 = G[1];
  if (bid < 2048) {
    const size_t i = (size_t)bid * 256 + threadIdx.x;
    const size_t c = i * 8;
    const int j0 = (int)(c & (DM - 1));
    const int b = (int)(c >> 20);
    u16x8 wv8 = *(const u16x8*)(woT + (c & ((1u << 20) - 1)));
    const float4 qa0 = *(const float4*)(qacc + b * DM + j0);
    const float4 qa1 = *(const float4*)(qacc + b * DM + j0 + 4);
    const float4 ka0 = *(const float4*)(kacc + b * DM + j0);
    const float4 ka1 = *(const float4*)(kacc + b * DM + j0 + 4);
    const float4 bq0 = *(const float4*)(bq + j0);
    const float4 bq1 = *(const float4*)(bq + j0 + 4);
    const float4 bk0 = *(const float4*)(bk + j0);
    const float4 bk1 = *(const float4*)(bk + j0 + 4);
    float qa[8] = {qa0.x, qa0.y, qa0.z, qa0.w, qa1.x, qa1.y, qa1.z, qa1.w};
    float ka[8] = {ka0.x, ka0.y, ka0.z, ka0.w, ka1.x, ka1.y, ka1.z, ka1.w};
    float bqv[8] = {bq0.x, bq0.y, bq0.z, bq0.w, bq1.x, bq1.y, bq1.z, bq1.w};
    float bkv[8] = {bk0.x, bk0.y, bk0.z, bk0.w, bk1.x, bk1.y, bk1.z, bk1.w};
    u16x8 o;
#pragma unroll
    for (int j = 0; j < 8; ++j) {
      const float gk = (qa[j] + bqv[j] * G0) * (ka[j] + bkv[j] * G1);
      o[j] = f2bf(bf2f(wv8[j]) * gk);
    }
    *(u16x8*)(wogT + i * 8) = o;
  } else {
    const int t = bid - 2048;            // 0..127: (dchunk 0..3, kchunk 0..31)
    const int n = (t & 3) * 256 + threadIdx.x;
    const int k0 = (t >> 2) * 32;
    float aq = 0.f, av[4] = {0.f, 0.f, 0.f, 0.f};
    for (int kk = 0; kk < 32; ++kk) {
      const int j = k0 + kk;
      const float w = wo[(size_t)j * DM + n];
      aq += bq[j] * w;
      const float bw = bv[j] * w;
      const float bqj = bq[j] * G0, bkj = bk[j] * G1;
#pragma unroll
      for (int b = 0; b < 4; ++b) {
        const float gkv = (qacc[b * DM + j] + bqj) * (kacc[b * DM + j] + bkj);
        av[b] += bw * gkv;
      }
    }
    atomicAdd(&qbias[n], aq);
#pragma unroll
    for (int b = 0; b < 4; ++b) atomicAdd(&vbias[b * DM + n], av[b]);
  }
}

// ---------------------------------------------------------------------------
// K_PIPE: read-ahead pipelined GEMM (R18-verified). BM=256 BN=128, 8 waves
// 4x2 (wave-tile 64x64, acc 4x4), 3-buf LDS. Per K-tile: 2 phases, ds_read of
// next phase before MFMA of current, ONE counted vmcnt+barrier per tile.
// MODE 0 (NT=32): K_eff=2048; f32 epilogue. Grid (32,8).
// MODE 1 (NT=16): weight GEMMs z=0..4; bf16 epilogue. Grid (4,8,5).
template <int MODE, int NT>
__global__ __launch_bounds__(512, 1)
void k_pipe(const ushort_t* __restrict__ A0, const ushort_t* __restrict__ B0,
            const ushort_t* __restrict__ A1, const ushort_t* __restrict__ B1,
            const float* __restrict__ gqw, const float* __restrict__ qbias,
            const float* __restrict__ vbias, const float* __restrict__ bo,
            void* __restrict__ OutV) {
  __shared__ __align__(16) ushort_t lsA[3][256 * 64];  // 3 x 32 KB
  __shared__ __align__(16) ushort_t lsB[3][128 * 64];  // 3 x 16 KB
  const int tid = threadIdx.x;
  const int w = tid >> 6, lane = tid & 63;
  const int m0 = blockIdx.x * 256, n0 = blockIdx.y * 128;
  const int b = (MODE == 0) ? (m0 >> 11) : 0;
  const int wr = w >> 1, wc = w & 1;  // 4x2 wave grid, per-wave 64x64 out

  const ushort_t *Aq, *Bq, *Av = nullptr, *Bv = nullptr;
  if constexpr (MODE == 0) {
    Aq = A0; Bq = B0; Av = A1; Bv = B1 + (size_t)b * (DM * DM);
  } else {
    const int z = blockIdx.z;
    Aq = z ? A1 + (size_t)(z - 1) * (DM * DM) : A0;
    Bq = z ? B1 : B0;
  }

  const int subrow = lane >> 3;
  const int srcslot = (lane & 7) ^ subrow;
  size_t offA[4], offB[2];
#pragma unroll
  for (int p = 0; p < 4; ++p) {
    const int row = (4 * w + p) * 8 + subrow;           // 0..255
    offA[p] = (size_t)(m0 + row) * DM + srcslot * 8;
  }
#pragma unroll
  for (int p = 0; p < 2; ++p) {
    const int row = (2 * w + p) * 8 + subrow;           // 0..127
    offB[p] = (size_t)(n0 + row) * DM + srcslot * 8;
  }

  const int g = lane >> 4, l7 = lane & 7, l15 = lane & 15;
  int aoff[2][4], boff[2][4];
#pragma unroll
  for (int kh = 0; kh < 2; ++kh) {
#pragma unroll
    for (int i = 0; i < 4; ++i) {
      const int ra = wr * 64 + i * 16 + l15;
      aoff[kh][i] = ra * 64 + (((kh * 4 + g) ^ l7) * 8);
    }
#pragma unroll
    for (int j = 0; j < 4; ++j) {
      const int rb = wc * 64 + j * 16 + l15;
      boff[kh][j] = rb * 64 + (((kh * 4 + g) ^ l7) * 8);
    }
  }

  f32x4 acc[4][4];
#pragma unroll
  for (int i = 0; i < 4; ++i)
#pragma unroll
    for (int j = 0; j < 4; ++j) acc[i][j] = (f32x4){0.f, 0.f, 0.f, 0.f};

  auto SRC = [&](int tt, const ushort_t*& Ab, const ushort_t*& Bb, int& k0) {
    if (MODE == 0 && tt >= NT / 2) { Ab = Av; Bb = Bv; k0 = (tt - NT / 2) * 64; }
    else                           { Ab = Aq; Bb = Bq; k0 = tt * 64; }
  };
  auto STAGE_H0 = [&](int tt, int buf) {
    const ushort_t *Ab, *Bb; int k0; SRC(tt, Ab, Bb, k0);
    GLL(Ab + offA[0] + k0, &lsA[buf][(4 * w + 0) * 512]);
    GLL(Ab + offA[1] + k0, &lsA[buf][(4 * w + 1) * 512]);
    GLL(Bb + offB[0] + k0, &lsB[buf][(2 * w + 0) * 512]);
  };
  auto STAGE_H1 = [&](int tt, int buf) {
    const ushort_t *Ab, *Bb; int k0; SRC(tt, Ab, Bb, k0);
    GLL(Ab + offA[2] + k0, &lsA[buf][(4 * w + 2) * 512]);
    GLL(Ab + offA[3] + k0, &lsA[buf][(4 * w + 3) * 512]);
    GLL(Bb + offB[1] + k0, &lsB[buf][(2 * w + 1) * 512]);
  };
  auto READF = [&](bf16x8 (&av)[4], bf16x8 (&bv)[4], int cur, int kh) {
#pragma unroll
    for (int i = 0; i < 4; ++i) av[i] = *(const bf16x8*)(&lsA[cur][aoff[kh][i]]);
#pragma unroll
    for (int j = 0; j < 4; ++j) bv[j] = *(const bf16x8*)(&lsB[cur][boff[kh][j]]);
  };
  auto DOMFMA = [&](bf16x8 (&av)[4], bf16x8 (&bv)[4]) {
    __builtin_amdgcn_s_setprio(1);
#pragma unroll
    for (int i = 0; i < 4; ++i)
#pragma unroll
      for (int j = 0; j < 4; ++j)
        acc[i][j] = __builtin_amdgcn_mfma_f32_16x16x32_bf16(av[i], bv[j], acc[i][j], 0, 0, 0);
    __builtin_amdgcn_s_setprio(0);
  };

  bf16x8 avA[4], bvA[4], avB[4], bvB[4];

  STAGE_H0(0, 0); STAGE_H1(0, 0);
  STAGE_H0(1, 1); STAGE_H1(1, 1);
  asm volatile("s_waitcnt vmcnt(6)" ::: "memory");
  __builtin_amdgcn_s_barrier();
  READF(avA, bvA, 0, 0);

#pragma unroll 1
  for (int t = 0; t < NT; ++t) {
    const int cur = t % 3, nb = (t + 2) % 3, nxt = (t + 1) % 3;
    READF(avB, bvB, cur, 1);
    if (t + 2 < NT) STAGE_H0(t + 2, nb);
    DOMFMA(avA, bvA);
    if (t + 1 < NT) {
      if (t + 2 < NT) { asm volatile("s_waitcnt vmcnt(3)\n\ts_barrier" ::: "memory"); }
      else            { asm volatile("s_waitcnt vmcnt(0)\n\ts_barrier" ::: "memory"); }
      READF(avA, bvA, nxt, 0);
      if (t + 2 < NT) STAGE_H1(t + 2, nb);
    }
    DOMFMA(avB, bvB);
  }

  const int lr = (lane >> 4) * 4, lc = lane & 15;
  const int rbase = m0 + wr * 64, cbase = n0 + wc * 64;
  if constexpr (MODE == 0) {
    float* Out = (float*)OutV;
#pragma unroll
    for (int j = 0; j < 4; ++j) {
      const int col = cbase + j * 16 + lc;
      const float qbn = qbias[col];
      const float cb = vbias[b * DM + col] + bo[col];
#pragma unroll
      for (int i = 0; i < 4; ++i)
#pragma unroll
        for (int r = 0; r < 4; ++r) {
          const int row = rbase + i * 16 + lr + r;
          Out[(size_t)row * DM + col] = acc[i][j][r] + gqw[row & (SEQ - 1)] * qbn + cb;
        }
    }
  } else {
    ushort_t* Out = (ushort_t*)OutV + (size_t)blockIdx.z * (DM * DM);
#pragma unroll
    for (int j = 0; j < 4; ++j) {
      const int col = cbase + j * 16 + lc;
#pragma unroll
      for (int i = 0; i < 4; ++i)
#pragma unroll
        for (int r = 0; r < 4; ++r) {
          const int row = rbase + i * 16 + lr + r;
          Out[(size_t)row * DM + col] = f2bf(acc[i][j][r]);
        }
    }
  }
}

// ---------------------------------------------------------------------------
extern "C" void kernel_launch(void* const* d_in, const int* in_sizes, int n_in,
                              void* d_out, int out_size, void* d_ws, size_t ws_size,
                              hipStream_t stream) {
  // input order: v k q mask wq bq wk bk wv bv gqw gkw wo bo
  const float* v   = (const float*)d_in[0];
  const float* k   = (const float*)d_in[1];
  const float* q   = (const float*)d_in[2];
  const float* wq  = (const float*)d_in[4];
  const float* bq  = (const float*)d_in[5];
  const float* wk  = (const float*)d_in[6];
  const float* bk  = (const float*)d_in[7];
  const float* wv  = (const float*)d_in[8];
  const float* bv  = (const float*)d_in[9];
  const float* gqw = (const float*)d_in[10];
  const float* gkw = (const float*)d_in[11];
  const float* wo  = (const float*)d_in[12];
  const float* bo  = (const float*)d_in[13];
  float* out = (float*)d_out;
  float* wsf = (float*)d_ws;

  // fp32 scratch: [qacc kacc | G | qbias | vbias]
  float* qacc  = wsf + 8192;
  float* kacc  = wsf + 12288;
  float* G     = wsf + 16384;   // 2 floats
  float* qbias = wsf + 16640;   // 1024
  float* vbias = wsf + 17664;   // 4096 (ends at 21760)
  // bf16 scratch at byte offset 128 KiB
  ushort_t* b16  = (ushort_t*)((char*)d_ws + (1 << 17));
  ushort_t* qb   = b16;                                 // 16MB gqw-scaled
  ushort_t* vb   = qb + (size_t)M_TOT * DM;             // 16MB
  ushort_t* wqB  = vb + (size_t)M_TOT * DM;             // 2MB
  ushort_t* wvB  = wqB + (size_t)DM * DM;               // 2MB
  ushort_t* woT  = wvB + (size_t)DM * DM;               // 2MB [N][K]
  ushort_t* WqoT = woT + (size_t)DM * DM;               // 2MB
  ushort_t* WvbT = WqoT + (size_t)DM * DM;              // 8MB [4][N][K]
  // dead d_out space hosts transient buffers (consumed before k_pipe<0> writes):
  ushort_t* wogT = (ushort_t*)out;       // [0, 8MB)
  float* pq = out + (1 << 22);           // [16, 18MB): 128 slots x 4 x 1024 f32
  float* pk = pq + (1 << 20);            // [20, 22MB)

  hipMemsetAsync((char*)d_ws + 8192 * sizeof(float), 0,
                 (21760 - 8192) * sizeof(float), stream);

  // merged weight preps (conv wq, conv wv, trans wo)
  k_wprep<<<2048, 256, 0, stream>>>(wq, wv, wo, wqB, wvB, woT);

  // data reductions + bf16 conversions (atomic-free partials)
  k_reduce<<<dim3(BATCH, SEQ / 16), 256, 0, stream>>>(q, k, v, gqw, gkw, pq, pk, G, qb, vb);

  // GEMV partials with inline partial-fold (k_rsum eliminated)
  k_gpart<<<dim3(DM / 256, DM / 32), 256, 0, stream>>>(wq, wk, pq, pk, qacc, kacc);

  // merged composed-weight prep + bias (gk inline)
  k_wogbias<<<2176, 256, 0, stream>>>(woT, wo, qacc, kacc, bq, bk, bv, G,
                                      wogT, qbias, vbias);

  // small GEMMs (pipelined, BM=256, 160 blocks): z=0 WqoT, z>0 WvbT[z-1]
  k_pipe<1, 16><<<dim3(4, 8, 5), 512, 0, stream>>>(
      woT, wqB, wogT, wvB, nullptr, nullptr, nullptr, nullptr, WqoT);

  // the one big GEMM -> out
  k_pipe<0, 32><<<dim3(M_TOT / 256, DM / 128), 512, 0, stream>>>(
      qb, WqoT, vb, WvbT, gqw, qbias, vbias, bo, out);
}

// Round 21
// 119.982 us; speedup vs baseline: 1.0399x; 1.0399x over previous
//
#include <hip/hip_runtime.h>

#define DM 1024
#define BATCH 4
#define SEQ 2048
#define M_TOT (BATCH*SEQ)

typedef unsigned short ushort_t;
typedef __bf16 bf16x8 __attribute__((ext_vector_type(8)));
typedef float f32x4 __attribute__((ext_vector_type(4)));
typedef unsigned short u16x4 __attribute__((ext_vector_type(4)));
typedef unsigned short u16x8 __attribute__((ext_vector_type(8)));

__device__ __forceinline__ ushort_t f2bf(float f) {
  unsigned u = __builtin_bit_cast(unsigned, f);
  u = (u + 0x7fffu + ((u >> 16) & 1u)) >> 16;
  return (ushort_t)u;
}
__device__ __forceinline__ float bf2f(ushort_t h) {
  unsigned u = ((unsigned)h) << 16;
  return __builtin_bit_cast(float, u);
}

// async global->LDS, 16B per lane, wave-uniform LDS base + lane*16
#define GLL(gp, lp)                                                            \
  __builtin_amdgcn_global_load_lds(                                            \
      (const __attribute__((address_space(1))) unsigned int*)(const void*)(gp),\
      (__attribute__((address_space(3))) unsigned int*)(void*)(lp), 16, 0, 0)

// ---------------------------------------------------------------------------
// K1 (ATOMIC-FREE): per-block partial sums over 16 rows, coalesced f4 stores;
// qb = bf16(gqw*q), vb = bf16(v). grid (BATCH, SEQ/16), block 256.
__global__ void k_reduce(const float* __restrict__ q, const float* __restrict__ k,
                         const float* __restrict__ v,
                         const float* __restrict__ gqw, const float* __restrict__ gkw,
                         float* __restrict__ pq, float* __restrict__ pk,
                         float* __restrict__ G,
                         ushort_t* __restrict__ qb, ushort_t* __restrict__ vb) {
  const int b = blockIdx.x, sc = blockIdx.y;   // sc: 0..127 (16-row chunks)
  const int d0 = threadIdx.x * 4;
  const int s0 = sc * 16;
  const size_t base = ((size_t)b * SEQ + s0) * DM + d0;
  float aq0 = 0.f, aq1 = 0.f, aq2 = 0.f, aq3 = 0.f;
  float ak0 = 0.f, ak1 = 0.f, ak2 = 0.f, ak3 = 0.f;
  float sgq = 0.f, sgk = 0.f;
#pragma unroll 4
  for (int i = 0; i < 16; ++i) {
    const float wq_ = gqw[s0 + i], wk_ = gkw[s0 + i];
    const size_t off = base + (size_t)i * DM;
    const float4 qv = *(const float4*)(q + off);
    const float4 kv = *(const float4*)(k + off);
    const float4 vv = *(const float4*)(v + off);
    aq0 += wq_ * qv.x; aq1 += wq_ * qv.y; aq2 += wq_ * qv.z; aq3 += wq_ * qv.w;
    ak0 += wk_ * kv.x; ak1 += wk_ * kv.y; ak2 += wk_ * kv.z; ak3 += wk_ * kv.w;
    u16x4 oq, ov;
    oq[0] = f2bf(wq_ * qv.x); oq[1] = f2bf(wq_ * qv.y);
    oq[2] = f2bf(wq_ * qv.z); oq[3] = f2bf(wq_ * qv.w);
    ov[0] = f2bf(vv.x); ov[1] = f2bf(vv.y); ov[2] = f2bf(vv.z); ov[3] = f2bf(vv.w);
    *(u16x4*)(qb + off) = oq;
    *(u16x4*)(vb + off) = ov;
    sgq += wq_; sgk += wk_;
  }
  const size_t po = ((size_t)(sc * BATCH + b) << 10) + d0;
  *(float4*)(pq + po) = make_float4(aq0, aq1, aq2, aq3);
  *(float4*)(pk + po) = make_float4(ak0, ak1, ak2, ak3);
  if (b == 0 && threadIdx.x == 0) {
    atomicAdd(&G[0], sgq);
    atomicAdd(&G[1], sgk);
  }
}

// K1b: fold 128 partial slots into qr/kr. grid (4,4,4), 16K atomics.
__global__ void k_rsum(const float* __restrict__ pq, const float* __restrict__ pk,
                       float* __restrict__ qr, float* __restrict__ kr) {
  const int b = blockIdx.x;
  const int d = blockIdx.y * 256 + threadIdx.x;
  const int sg = blockIdx.z;
  float aq = 0.f, ak = 0.f;
#pragma unroll 4
  for (int s = sg * 32; s < sg * 32 + 32; ++s) {
    const size_t po = ((size_t)(s * BATCH + b) << 10) + d;
    aq += pq[po];
    ak += pk[po];
  }
  atomicAdd(&qr[b * DM + d], aq);
  atomicAdd(&kr[b * DM + d], ak);
}

// K2: partial GEMV over K-chunks
__global__ void k_gpart(const float* __restrict__ wq, const float* __restrict__ wk,
                        const float* __restrict__ qr, const float* __restrict__ kr,
                        float* __restrict__ qacc, float* __restrict__ kacc) {
  const int d = blockIdx.x * 256 + threadIdx.x;
  const int k0 = blockIdx.y * 32;
  __shared__ float sq[4][32], sk[4][32];
  if (threadIdx.x < 128) {
    const int b = threadIdx.x >> 5, kk = threadIdx.x & 31;
    sq[b][kk] = qr[b * DM + k0 + kk];
    sk[b][kk] = kr[b * DM + k0 + kk];
  }
  __syncthreads();
  float aq[4] = {0.f, 0.f, 0.f, 0.f}, ak[4] = {0.f, 0.f, 0.f, 0.f};
#pragma unroll 8
  for (int kk = 0; kk < 32; ++kk) {
    const float wqv = wq[(size_t)(k0 + kk) * DM + d];
    const float wkv = wk[(size_t)(k0 + kk) * DM + d];
#pragma unroll
    for (int b = 0; b < 4; ++b) {
      aq[b] += sq[b][kk] * wqv;
      ak[b] += sk[b][kk] * wkv;
    }
  }
#pragma unroll
  for (int b = 0; b < 4; ++b) {
    atomicAdd(&qacc[b * DM + d], aq[b]);
    atomicAdd(&kacc[b * DM + d], ak[b]);
  }
}

// K3: merged weight prep. 1D grid 2048: [0,512) conv wq->wqB; [512,1024)
// conv wv->wvB; [1024,2048) transpose-convert wo->woT.
__global__ void k_wprep(const float* __restrict__ wq, const float* __restrict__ wv,
                        const float* __restrict__ wo,
                        ushort_t* __restrict__ wqB, ushort_t* __restrict__ wvB,
                        ushort_t* __restrict__ woT) {
  const int bid = blockIdx.x;
  if (bid < 1024) {
    const float* x = bid < 512 ? wq : wv;
    ushort_t* y = bid < 512 ? wqB : wvB;
    size_t i = (size_t)(bid & 511) * 256 + threadIdx.x;
    const float4* p = (const float4*)x + i * 2;
    float4 a = p[0], bb = p[1];
    u16x8 o;
    o[0] = f2bf(a.x); o[1] = f2bf(a.y); o[2] = f2bf(a.z); o[3] = f2bf(a.w);
    o[4] = f2bf(bb.x); o[5] = f2bf(bb.y); o[6] = f2bf(bb.z); o[7] = f2bf(bb.w);
    *(u16x8*)(y + i * 8) = o;
  } else {
    __shared__ float ls[32][33];
    const int t = bid - 1024;
    const int bi = t >> 5, bj = t & 31;
#pragma unroll
    for (int p = 0; p < 4; ++p) {
      int e = threadIdx.x + p * 256;
      int r = e >> 5, c = e & 31;
      ls[r][c] = wo[(size_t)(bi * 32 + r) * DM + bj * 32 + c];
    }
    __syncthreads();
#pragma unroll
    for (int p = 0; p < 4; ++p) {
      int e = threadIdx.x + p * 256;
      int r = e >> 5, c = e & 31;
      woT[(size_t)(bj * 32 + r) * DM + bi * 32 + c] = f2bf(ls[c][r]);
    }
  }
}

// K5: wogT[b][n][j] = woT[n][j] * gk[b][j], gk computed inline from
// qacc/kacc/bq/bk/G (k_gfin folded in).
__global__ void k_wog(const ushort_t* __restrict__ woT,
                      const float* __restrict__ qacc, const float* __restrict__ kacc,
                      const float* __restrict__ bq, const float* __restrict__ bk,
                      const float* __restrict__ G, ushort_t* __restrict__ wogT) {
  const size_t i = (size_t)blockIdx.x * 256 + threadIdx.x;
  const size_t c = i * 8;
  const int j0 = (int)(c & (DM - 1));
  const int b = (int)(c >> 20);
  const float G0 = G[0], G1 = G[1];
  u16x8 wv8 = *(const u16x8*)(woT + (c & ((1u << 20) - 1)));
  const float4 qa0 = *(const float4*)(qacc + b * DM + j0);
  const float4 qa1 = *(const float4*)(qacc + b * DM + j0 + 4);
  const float4 ka0 = *(const float4*)(kacc + b * DM + j0);
  const float4 ka1 = *(const float4*)(kacc + b * DM + j0 + 4);
  const float4 bq0 = *(const float4*)(bq + j0);
  const float4 bq1 = *(const float4*)(bq + j0 + 4);
  const float4 bk0 = *(const float4*)(bk + j0);
  const float4 bk1 = *(const float4*)(bk + j0 + 4);
  float qa[8] = {qa0.x, qa0.y, qa0.z, qa0.w, qa1.x, qa1.y, qa1.z, qa1.w};
  float ka[8] = {ka0.x, ka0.y, ka0.z, ka0.w, ka1.x, ka1.y, ka1.z, ka1.w};
  float bqv[8] = {bq0.x, bq0.y, bq0.z, bq0.w, bq1.x, bq1.y, bq1.z, bq1.w};
  float bkv[8] = {bk0.x, bk0.y, bk0.z, bk0.w, bk1.x, bk1.y, bk1.z, bk1.w};
  u16x8 o;
#pragma unroll
  for (int j = 0; j < 8; ++j) {
    const float gk = (qa[j] + bqv[j] * G0) * (ka[j] + bkv[j] * G1);
    o[j] = f2bf(bf2f(wv8[j]) * gk);
  }
  *(u16x8*)(wogT + i * 8) = o;
}

// K6: qbias[n] = sum_j bq[j]*wo[j,n]; vbias[b][n] = sum_j bv[j]*gk[b][j]*wo[j,n]
// with gk inline (k_gfin folded in).
__global__ void k_bias(const float* __restrict__ wo, const float* __restrict__ bq,
                       const float* __restrict__ bk, const float* __restrict__ bv,
                       const float* __restrict__ qacc, const float* __restrict__ kacc,
                       const float* __restrict__ G,
                       float* __restrict__ qbias, float* __restrict__ vbias) {
  const int n = blockIdx.x * 256 + threadIdx.x;
  const int k0 = blockIdx.y * 32;
  const float G0 = G[0], G1 = G[1];
  float aq = 0.f, av[4] = {0.f, 0.f, 0.f, 0.f};
  for (int kk = 0; kk < 32; ++kk) {
    const int j = k0 + kk;
    const float w = wo[(size_t)j * DM + n];
    aq += bq[j] * w;
    const float bw = bv[j] * w;
    const float bqj = bq[j] * G0, bkj = bk[j] * G1;
#pragma unroll
    for (int b = 0; b < 4; ++b) {
      const float gkv = (qacc[b * DM + j] + bqj) * (kacc[b * DM + j] + bkj);
      av[b] += bw * gkv;
    }
  }
  atomicAdd(&qbias[n], aq);
#pragma unroll
  for (int b = 0; b < 4; ++b) atomicAdd(&vbias[b * DM + n], av[b]);
}

// ---------------------------------------------------------------------------
// K_PIPE: read-ahead pipelined GEMM (R18-verified). BM=256 BN=128, 8 waves
// 4x2 (wave-tile 64x64, acc 4x4), 3-buf LDS. Per K-tile: 2 phases, ds_read of
// next phase before MFMA of current, ONE counted vmcnt+barrier per tile.
// MODE 0 (NT=32): K_eff=2048; f32 epilogue. Grid (32,8).
// MODE 1 (NT=16): weight GEMMs z=0..4; bf16 epilogue. Grid (4,8,5).
template <int MODE, int NT>
__global__ __launch_bounds__(512, 1)
void k_pipe(const ushort_t* __restrict__ A0, const ushort_t* __restrict__ B0,
            const ushort_t* __restrict__ A1, const ushort_t* __restrict__ B1,
            const float* __restrict__ gqw, const float* __restrict__ qbias,
            const float* __restrict__ vbias, const float* __restrict__ bo,
            void* __restrict__ OutV) {
  __shared__ __align__(16) ushort_t lsA[3][256 * 64];  // 3 x 32 KB
  __shared__ __align__(16) ushort_t lsB[3][128 * 64];  // 3 x 16 KB
  const int tid = threadIdx.x;
  const int w = tid >> 6, lane = tid & 63;
  const int m0 = blockIdx.x * 256, n0 = blockIdx.y * 128;
  const int b = (MODE == 0) ? (m0 >> 11) : 0;
  const int wr = w >> 1, wc = w & 1;  // 4x2 wave grid, per-wave 64x64 out

  const ushort_t *Aq, *Bq, *Av = nullptr, *Bv = nullptr;
  if constexpr (MODE == 0) {
    Aq = A0; Bq = B0; Av = A1; Bv = B1 + (size_t)b * (DM * DM);
  } else {
    const int z = blockIdx.z;
    Aq = z ? A1 + (size_t)(z - 1) * (DM * DM) : A0;
    Bq = z ? B1 : B0;
  }

  const int subrow = lane >> 3;
  const int srcslot = (lane & 7) ^ subrow;
  size_t offA[4], offB[2];
#pragma unroll
  for (int p = 0; p < 4; ++p) {
    const int row = (4 * w + p) * 8 + subrow;           // 0..255
    offA[p] = (size_t)(m0 + row) * DM + srcslot * 8;
  }
#pragma unroll
  for (int p = 0; p < 2; ++p) {
    const int row = (2 * w + p) * 8 + subrow;           // 0..127
    offB[p] = (size_t)(n0 + row) * DM + srcslot * 8;
  }

  const int g = lane >> 4, l7 = lane & 7, l15 = lane & 15;
  int aoff[2][4], boff[2][4];
#pragma unroll
  for (int kh = 0; kh < 2; ++kh) {
#pragma unroll
    for (int i = 0; i < 4; ++i) {
      const int ra = wr * 64 + i * 16 + l15;
      aoff[kh][i] = ra * 64 + (((kh * 4 + g) ^ l7) * 8);
    }
#pragma unroll
    for (int j = 0; j < 4; ++j) {
      const int rb = wc * 64 + j * 16 + l15;
      boff[kh][j] = rb * 64 + (((kh * 4 + g) ^ l7) * 8);
    }
  }

  f32x4 acc[4][4];
#pragma unroll
  for (int i = 0; i < 4; ++i)
#pragma unroll
    for (int j = 0; j < 4; ++j) acc[i][j] = (f32x4){0.f, 0.f, 0.f, 0.f};

  auto SRC = [&](int tt, const ushort_t*& Ab, const ushort_t*& Bb, int& k0) {
    if (MODE == 0 && tt >= NT / 2) { Ab = Av; Bb = Bv; k0 = (tt - NT / 2) * 64; }
    else                           { Ab = Aq; Bb = Bq; k0 = tt * 64; }
  };
  auto STAGE_H0 = [&](int tt, int buf) {
    const ushort_t *Ab, *Bb; int k0; SRC(tt, Ab, Bb, k0);
    GLL(Ab + offA[0] + k0, &lsA[buf][(4 * w + 0) * 512]);
    GLL(Ab + offA[1] + k0, &lsA[buf][(4 * w + 1) * 512]);
    GLL(Bb + offB[0] + k0, &lsB[buf][(2 * w + 0) * 512]);
  };
  auto STAGE_H1 = [&](int tt, int buf) {
    const ushort_t *Ab, *Bb; int k0; SRC(tt, Ab, Bb, k0);
    GLL(Ab + offA[2] + k0, &lsA[buf][(4 * w + 2) * 512]);
    GLL(Ab + offA[3] + k0, &lsA[buf][(4 * w + 3) * 512]);
    GLL(Bb + offB[1] + k0, &lsB[buf][(2 * w + 1) * 512]);
  };
  auto READF = [&](bf16x8 (&av)[4], bf16x8 (&bv)[4], int cur, int kh) {
#pragma unroll
    for (int i = 0; i < 4; ++i) av[i] = *(const bf16x8*)(&lsA[cur][aoff[kh][i]]);
#pragma unroll
    for (int j = 0; j < 4; ++j) bv[j] = *(const bf16x8*)(&lsB[cur][boff[kh][j]]);
  };
  auto DOMFMA = [&](bf16x8 (&av)[4], bf16x8 (&bv)[4]) {
    __builtin_amdgcn_s_setprio(1);
#pragma unroll
    for (int i = 0; i < 4; ++i)
#pragma unroll
      for (int j = 0; j < 4; ++j)
        acc[i][j] = __builtin_amdgcn_mfma_f32_16x16x32_bf16(av[i], bv[j], acc[i][j], 0, 0, 0);
    __builtin_amdgcn_s_setprio(0);
  };

  bf16x8 avA[4], bvA[4], avB[4], bvB[4];

  STAGE_H0(0, 0); STAGE_H1(0, 0);
  STAGE_H0(1, 1); STAGE_H1(1, 1);
  asm volatile("s_waitcnt vmcnt(6)" ::: "memory");
  __builtin_amdgcn_s_barrier();
  READF(avA, bvA, 0, 0);

#pragma unroll 1
  for (int t = 0; t < NT; ++t) {
    const int cur = t % 3, nb = (t + 2) % 3, nxt = (t + 1) % 3;
    READF(avB, bvB, cur, 1);
    if (t + 2 < NT) STAGE_H0(t + 2, nb);
    DOMFMA(avA, bvA);
    if (t + 1 < NT) {
      if (t + 2 < NT) { asm volatile("s_waitcnt vmcnt(3)\n\ts_barrier" ::: "memory"); }
      else            { asm volatile("s_waitcnt vmcnt(0)\n\ts_barrier" ::: "memory"); }
      READF(avA, bvA, nxt, 0);
      if (t + 2 < NT) STAGE_H1(t + 2, nb);
    }
    DOMFMA(avB, bvB);
  }

  const int lr = (lane >> 4) * 4, lc = lane & 15;
  const int rbase = m0 + wr * 64, cbase = n0 + wc * 64;
  if constexpr (MODE == 0) {
    float* Out = (float*)OutV;
#pragma unroll
    for (int j = 0; j < 4; ++j) {
      const int col = cbase + j * 16 + lc;
      const float qbn = qbias[col];
      const float cb = vbias[b * DM + col] + bo[col];
#pragma unroll
      for (int i = 0; i < 4; ++i)
#pragma unroll
        for (int r = 0; r < 4; ++r) {
          const int row = rbase + i * 16 + lr + r;
          Out[(size_t)row * DM + col] = acc[i][j][r] + gqw[row & (SEQ - 1)] * qbn + cb;
        }
    }
  } else {
    ushort_t* Out = (ushort_t*)OutV + (size_t)blockIdx.z * (DM * DM);
#pragma unroll
    for (int j = 0; j < 4; ++j) {
      const int col = cbase + j * 16 + lc;
#pragma unroll
      for (int i = 0; i < 4; ++i)
#pragma unroll
        for (int r = 0; r < 4; ++r) {
          const int row = rbase + i * 16 + lr + r;
          Out[(size_t)row * DM + col] = f2bf(acc[i][j][r]);
        }
    }
  }
}

// ---------------------------------------------------------------------------
extern "C" void kernel_launch(void* const* d_in, const int* in_sizes, int n_in,
                              void* d_out, int out_size, void* d_ws, size_t ws_size,
                              hipStream_t stream) {
  // input order: v k q mask wq bq wk bk wv bv gqw gkw wo bo
  const float* v   = (const float*)d_in[0];
  const float* k   = (const float*)d_in[1];
  const float* q   = (const float*)d_in[2];
  const float* wq  = (const float*)d_in[4];
  const float* bq  = (const float*)d_in[5];
  const float* wk  = (const float*)d_in[6];
  const float* bk  = (const float*)d_in[7];
  const float* wv  = (const float*)d_in[8];
  const float* bv  = (const float*)d_in[9];
  const float* gqw = (const float*)d_in[10];
  const float* gkw = (const float*)d_in[11];
  const float* wo  = (const float*)d_in[12];
  const float* bo  = (const float*)d_in[13];
  float* out = (float*)d_out;
  float* wsf = (float*)d_ws;

  // fp32 scratch: [qr kr qacc kacc | G | qbias | vbias]
  float* qr    = wsf + 0;
  float* kr    = wsf + 4096;
  float* qacc  = wsf + 8192;
  float* kacc  = wsf + 12288;
  float* G     = wsf + 16384;   // 2 floats
  float* qbias = wsf + 16640;   // 1024
  float* vbias = wsf + 17664;   // 4096 (ends at 21760)
  // bf16 scratch at byte offset 128 KiB
  ushort_t* b16  = (ushort_t*)((char*)d_ws + (1 << 17));
  ushort_t* qb   = b16;                                 // 16MB gqw-scaled
  ushort_t* vb   = qb + (size_t)M_TOT * DM;             // 16MB
  ushort_t* wqB  = vb + (size_t)M_TOT * DM;             // 2MB
  ushort_t* wvB  = wqB + (size_t)DM * DM;               // 2MB
  ushort_t* woT  = wvB + (size_t)DM * DM;               // 2MB [N][K]
  ushort_t* WqoT = woT + (size_t)DM * DM;               // 2MB
  ushort_t* WvbT = WqoT + (size_t)DM * DM;              // 8MB [4][N][K]
  // dead d_out space hosts transient buffers (consumed before k_pipe<0> writes):
  ushort_t* wogT = (ushort_t*)out;       // [0, 8MB)
  float* pq = out + (1 << 22);           // [16, 18MB): 128 slots x 4 x 1024 f32
  float* pk = pq + (1 << 20);            // [20, 22MB)

  hipMemsetAsync(d_ws, 0, 21760 * sizeof(float), stream);

  // merged weight preps (conv wq, conv wv, trans wo)
  k_wprep<<<2048, 256, 0, stream>>>(wq, wv, wo, wqB, wvB, woT);

  // data reductions + bf16 conversions (atomic-free partials)
  k_reduce<<<dim3(BATCH, SEQ / 16), 256, 0, stream>>>(q, k, v, gqw, gkw, pq, pk, G, qb, vb);
  k_rsum<<<dim3(BATCH, DM / 256, 4), 256, 0, stream>>>(pq, pk, qr, kr);

  // global-vector GEMV partials
  k_gpart<<<dim3(DM / 256, DM / 32), 256, 0, stream>>>(wq, wk, qr, kr, qacc, kacc);

  // composed-weight preps (gk computed inline; k_gfin eliminated)
  k_wog<<<(BATCH * DM * DM / 8) / 256, 256, 0, stream>>>(woT, qacc, kacc, bq, bk, G, wogT);
  k_bias<<<dim3(DM / 256, DM / 32), 256, 0, stream>>>(wo, bq, bk, bv, qacc, kacc, G, qbias, vbias);

  // small GEMMs (pipelined, BM=256, 160 blocks): z=0 WqoT, z>0 WvbT[z-1]
  k_pipe<1, 16><<<dim3(4, 8, 5), 512, 0, stream>>>(
      woT, wqB, wogT, wvB, nullptr, nullptr, nullptr, nullptr, WqoT);

  // the one big GEMM -> out
  k_pipe<0, 32><<<dim3(M_TOT / 256, DM / 128), 512, 0, stream>>>(
      qb, WqoT, vb, WvbT, gqw, qbias, vbias, bo, out);
}

// Round 22
// 116.800 us; speedup vs baseline: 1.0683x; 1.0272x over previous
//
#include <hip/hip_runtime.h>

#define DM 1024
#define BATCH 4
#define SEQ 2048
#define M_TOT (BATCH*SEQ)

typedef unsigned short ushort_t;
typedef __bf16 bf16x8 __attribute__((ext_vector_type(8)));
typedef float f32x4 __attribute__((ext_vector_type(4)));
typedef unsigned short u16x4 __attribute__((ext_vector_type(4)));
typedef unsigned short u16x8 __attribute__((ext_vector_type(8)));

__device__ __forceinline__ ushort_t f2bf(float f) {
  unsigned u = __builtin_bit_cast(unsigned, f);
  u = (u + 0x7fffu + ((u >> 16) & 1u)) >> 16;
  return (ushort_t)u;
}
__device__ __forceinline__ float bf2f(ushort_t h) {
  unsigned u = ((unsigned)h) << 16;
  return __builtin_bit_cast(float, u);
}

// async global->LDS, 16B per lane, wave-uniform LDS base + lane*16
#define GLL(gp, lp)                                                            \
  __builtin_amdgcn_global_load_lds(                                            \
      (const __attribute__((address_space(1))) unsigned int*)(const void*)(gp),\
      (__attribute__((address_space(3))) unsigned int*)(void*)(lp), 16, 0, 0)

// ---------------------------------------------------------------------------
// K1 (MERGED, independent work): 1D grid 2560.
// [0,512):    k_reduce body (b = bid&3, sc = bid>>2): partial sums + qb/vb
// [512,1024): conv wq->wqB   [1024,1536): conv wv->wvB
// [1536,2560): transpose-convert wo->woT
__global__ void k_prep_reduce(const float* __restrict__ q, const float* __restrict__ k,
                              const float* __restrict__ v,
                              const float* __restrict__ gqw, const float* __restrict__ gkw,
                              const float* __restrict__ wq, const float* __restrict__ wv,
                              const float* __restrict__ wo,
                              float* __restrict__ pq, float* __restrict__ pk,
                              float* __restrict__ G,
                              ushort_t* __restrict__ qb, ushort_t* __restrict__ vb,
                              ushort_t* __restrict__ wqB, ushort_t* __restrict__ wvB,
                              ushort_t* __restrict__ woT) {
  const int bid = blockIdx.x;
  if (bid < 512) {
    const int b = bid & 3, sc = bid >> 2;   // sc: 0..127 (16-row chunks)
    const int d0 = threadIdx.x * 4;
    const int s0 = sc * 16;
    const size_t base = ((size_t)b * SEQ + s0) * DM + d0;
    float aq0 = 0.f, aq1 = 0.f, aq2 = 0.f, aq3 = 0.f;
    float ak0 = 0.f, ak1 = 0.f, ak2 = 0.f, ak3 = 0.f;
    float sgq = 0.f, sgk = 0.f;
#pragma unroll 4
    for (int i = 0; i < 16; ++i) {
      const float wq_ = gqw[s0 + i], wk_ = gkw[s0 + i];
      const size_t off = base + (size_t)i * DM;
      const float4 qv = *(const float4*)(q + off);
      const float4 kv = *(const float4*)(k + off);
      const float4 vv = *(const float4*)(v + off);
      aq0 += wq_ * qv.x; aq1 += wq_ * qv.y; aq2 += wq_ * qv.z; aq3 += wq_ * qv.w;
      ak0 += wk_ * kv.x; ak1 += wk_ * kv.y; ak2 += wk_ * kv.z; ak3 += wk_ * kv.w;
      u16x4 oq, ov;
      oq[0] = f2bf(wq_ * qv.x); oq[1] = f2bf(wq_ * qv.y);
      oq[2] = f2bf(wq_ * qv.z); oq[3] = f2bf(wq_ * qv.w);
      ov[0] = f2bf(vv.x); ov[1] = f2bf(vv.y); ov[2] = f2bf(vv.z); ov[3] = f2bf(vv.w);
      *(u16x4*)(qb + off) = oq;
      *(u16x4*)(vb + off) = ov;
      sgq += wq_; sgk += wk_;
    }
    const size_t po = ((size_t)(sc * BATCH + b) << 10) + d0;
    *(float4*)(pq + po) = make_float4(aq0, aq1, aq2, aq3);
    *(float4*)(pk + po) = make_float4(ak0, ak1, ak2, ak3);
    if (b == 0 && threadIdx.x == 0) {
      atomicAdd(&G[0], sgq);
      atomicAdd(&G[1], sgk);
    }
  } else if (bid < 1536) {
    const float* x = bid < 1024 ? wq : wv;
    ushort_t* y = bid < 1024 ? wqB : wvB;
    size_t i = (size_t)((bid - 512) & 511) * 256 + threadIdx.x;
    const float4* p = (const float4*)x + i * 2;
    float4 a = p[0], bb = p[1];
    u16x8 o;
    o[0] = f2bf(a.x); o[1] = f2bf(a.y); o[2] = f2bf(a.z); o[3] = f2bf(a.w);
    o[4] = f2bf(bb.x); o[5] = f2bf(bb.y); o[6] = f2bf(bb.z); o[7] = f2bf(bb.w);
    *(u16x8*)(y + i * 8) = o;
  } else {
    __shared__ float ls[32][33];
    const int t = bid - 1536;
    const int bi = t >> 5, bj = t & 31;
#pragma unroll
    for (int p = 0; p < 4; ++p) {
      int e = threadIdx.x + p * 256;
      int r = e >> 5, c = e & 31;
      ls[r][c] = wo[(size_t)(bi * 32 + r) * DM + bj * 32 + c];
    }
    __syncthreads();
#pragma unroll
    for (int p = 0; p < 4; ++p) {
      int e = threadIdx.x + p * 256;
      int r = e >> 5, c = e & 31;
      woT[(size_t)(bj * 32 + r) * DM + bi * 32 + c] = f2bf(ls[c][r]);
    }
  }
}

// K1b: fold 128 partial slots into qr/kr. grid (4,4,4), 16K atomics.
__global__ void k_rsum(const float* __restrict__ pq, const float* __restrict__ pk,
                       float* __restrict__ qr, float* __restrict__ kr) {
  const int b = blockIdx.x;
  const int d = blockIdx.y * 256 + threadIdx.x;
  const int sg = blockIdx.z;
  float aq = 0.f, ak = 0.f;
#pragma unroll 4
  for (int s = sg * 32; s < sg * 32 + 32; ++s) {
    const size_t po = ((size_t)(s * BATCH + b) << 10) + d;
    aq += pq[po];
    ak += pk[po];
  }
  atomicAdd(&qr[b * DM + d], aq);
  atomicAdd(&kr[b * DM + d], ak);
}

// K2: partial GEMV over K-chunks (R19-verified)
__global__ void k_gpart(const float* __restrict__ wq, const float* __restrict__ wk,
                        const float* __restrict__ qr, const float* __restrict__ kr,
                        float* __restrict__ qacc, float* __restrict__ kacc) {
  const int d = blockIdx.x * 256 + threadIdx.x;
  const int k0 = blockIdx.y * 32;
  __shared__ float sq[4][32], sk[4][32];
  if (threadIdx.x < 128) {
    const int b = threadIdx.x >> 5, kk = threadIdx.x & 31;
    sq[b][kk] = qr[b * DM + k0 + kk];
    sk[b][kk] = kr[b * DM + k0 + kk];
  }
  __syncthreads();
  float aq[4] = {0.f, 0.f, 0.f, 0.f}, ak[4] = {0.f, 0.f, 0.f, 0.f};
#pragma unroll 8
  for (int kk = 0; kk < 32; ++kk) {
    const float wqv = wq[(size_t)(k0 + kk) * DM + d];
    const float wkv = wk[(size_t)(k0 + kk) * DM + d];
#pragma unroll
    for (int b = 0; b < 4; ++b) {
      aq[b] += sq[b][kk] * wqv;
      ak[b] += sk[b][kk] * wkv;
    }
  }
#pragma unroll
  for (int b = 0; b < 4; ++b) {
    atomicAdd(&qacc[b * DM + d], aq[b]);
    atomicAdd(&kacc[b * DM + d], ak[b]);
  }
}

// K4: merged wog + bias (independent work; 1D grid 2176, branch at 2048).
// [0,2048):  wogT[b][n][j] = woT[n][j] * gk[b][j]   (gk inline)
// [2048,2176): qbias / vbias reductions (gk inline)
__global__ void k_wogbias(const ushort_t* __restrict__ woT, const float* __restrict__ wo,
                          const float* __restrict__ qacc, const float* __restrict__ kacc,
                          const float* __restrict__ bq, const float* __restrict__ bk,
                          const float* __restrict__ bv, const float* __restrict__ G,
                          ushort_t* __restrict__ wogT,
                          float* __restrict__ qbias, float* __restrict__ vbias) {
  const int bid = blockIdx.x;
  const float G0 = G[0], G1 = G[1];
  if (bid < 2048) {
    const size_t i = (size_t)bid * 256 + threadIdx.x;
    const size_t c = i * 8;
    const int j0 = (int)(c & (DM - 1));
    const int b = (int)(c >> 20);
    u16x8 wv8 = *(const u16x8*)(woT + (c & ((1u << 20) - 1)));
    const float4 qa0 = *(const float4*)(qacc + b * DM + j0);
    const float4 qa1 = *(const float4*)(qacc + b * DM + j0 + 4);
    const float4 ka0 = *(const float4*)(kacc + b * DM + j0);
    const float4 ka1 = *(const float4*)(kacc + b * DM + j0 + 4);
    const float4 bq0 = *(const float4*)(bq + j0);
    const float4 bq1 = *(const float4*)(bq + j0 + 4);
    const float4 bk0 = *(const float4*)(bk + j0);
    const float4 bk1 = *(const float4*)(bk + j0 + 4);
    float qa[8] = {qa0.x, qa0.y, qa0.z, qa0.w, qa1.x, qa1.y, qa1.z, qa1.w};
    float ka[8] = {ka0.x, ka0.y, ka0.z, ka0.w, ka1.x, ka1.y, ka1.z, ka1.w};
    float bqv[8] = {bq0.x, bq0.y, bq0.z, bq0.w, bq1.x, bq1.y, bq1.z, bq1.w};
    float bkv[8] = {bk0.x, bk0.y, bk0.z, bk0.w, bk1.x, bk1.y, bk1.z, bk1.w};
    u16x8 o;
#pragma unroll
    for (int j = 0; j < 8; ++j) {
      const float gk = (qa[j] + bqv[j] * G0) * (ka[j] + bkv[j] * G1);
      o[j] = f2bf(bf2f(wv8[j]) * gk);
    }
    *(u16x8*)(wogT + i * 8) = o;
  } else {
    const int t = bid - 2048;            // 0..127: (dchunk 0..3, kchunk 0..31)
    const int n = (t & 3) * 256 + threadIdx.x;
    const int k0 = (t >> 2) * 32;
    float aq = 0.f, av[4] = {0.f, 0.f, 0.f, 0.f};
    for (int kk = 0; kk < 32; ++kk) {
      const int j = k0 + kk;
      const float w = wo[(size_t)j * DM + n];
      aq += bq[j] * w;
      const float bw = bv[j] * w;
      const float bqj = bq[j] * G0, bkj = bk[j] * G1;
#pragma unroll
      for (int b = 0; b < 4; ++b) {
        const float gkv = (qacc[b * DM + j] + bqj) * (kacc[b * DM + j] + bkj);
        av[b] += bw * gkv;
      }
    }
    atomicAdd(&qbias[n], aq);
#pragma unroll
    for (int b = 0; b < 4; ++b) atomicAdd(&vbias[b * DM + n], av[b]);
  }
}

// ---------------------------------------------------------------------------
// K_PIPE: read-ahead pipelined GEMM (R18-verified). BM=256 BN=128, 8 waves
// 4x2 (wave-tile 64x64, acc 4x4), 3-buf LDS. Per K-tile: 2 phases, ds_read of
// next phase before MFMA of current, ONE counted vmcnt+barrier per tile.
// MODE 0 (NT=32): K_eff=2048; f32 epilogue. Grid (32,8).
// MODE 1 (NT=16): weight GEMMs z=0..4; bf16 epilogue. Grid (4,8,5).
template <int MODE, int NT>
__global__ __launch_bounds__(512, 1)
void k_pipe(const ushort_t* __restrict__ A0, const ushort_t* __restrict__ B0,
            const ushort_t* __restrict__ A1, const ushort_t* __restrict__ B1,
            const float* __restrict__ gqw, const float* __restrict__ qbias,
            const float* __restrict__ vbias, const float* __restrict__ bo,
            void* __restrict__ OutV) {
  __shared__ __align__(16) ushort_t lsA[3][256 * 64];  // 3 x 32 KB
  __shared__ __align__(16) ushort_t lsB[3][128 * 64];  // 3 x 16 KB
  const int tid = threadIdx.x;
  const int w = tid >> 6, lane = tid & 63;
  const int m0 = blockIdx.x * 256, n0 = blockIdx.y * 128;
  const int b = (MODE == 0) ? (m0 >> 11) : 0;
  const int wr = w >> 1, wc = w & 1;  // 4x2 wave grid, per-wave 64x64 out

  const ushort_t *Aq, *Bq, *Av = nullptr, *Bv = nullptr;
  if constexpr (MODE == 0) {
    Aq = A0; Bq = B0; Av = A1; Bv = B1 + (size_t)b * (DM * DM);
  } else {
    const int z = blockIdx.z;
    Aq = z ? A1 + (size_t)(z - 1) * (DM * DM) : A0;
    Bq = z ? B1 : B0;
  }

  const int subrow = lane >> 3;
  const int srcslot = (lane & 7) ^ subrow;
  size_t offA[4], offB[2];
#pragma unroll
  for (int p = 0; p < 4; ++p) {
    const int row = (4 * w + p) * 8 + subrow;           // 0..255
    offA[p] = (size_t)(m0 + row) * DM + srcslot * 8;
  }
#pragma unroll
  for (int p = 0; p < 2; ++p) {
    const int row = (2 * w + p) * 8 + subrow;           // 0..127
    offB[p] = (size_t)(n0 + row) * DM + srcslot * 8;
  }

  const int g = lane >> 4, l7 = lane & 7, l15 = lane & 15;
  int aoff[2][4], boff[2][4];
#pragma unroll
  for (int kh = 0; kh < 2; ++kh) {
#pragma unroll
    for (int i = 0; i < 4; ++i) {
      const int ra = wr * 64 + i * 16 + l15;
      aoff[kh][i] = ra * 64 + (((kh * 4 + g) ^ l7) * 8);
    }
#pragma unroll
    for (int j = 0; j < 4; ++j) {
      const int rb = wc * 64 + j * 16 + l15;
      boff[kh][j] = rb * 64 + (((kh * 4 + g) ^ l7) * 8);
    }
  }

  f32x4 acc[4][4];
#pragma unroll
  for (int i = 0; i < 4; ++i)
#pragma unroll
    for (int j = 0; j < 4; ++j) acc[i][j] = (f32x4){0.f, 0.f, 0.f, 0.f};

  auto SRC = [&](int tt, const ushort_t*& Ab, const ushort_t*& Bb, int& k0) {
    if (MODE == 0 && tt >= NT / 2) { Ab = Av; Bb = Bv; k0 = (tt - NT / 2) * 64; }
    else                           { Ab = Aq; Bb = Bq; k0 = tt * 64; }
  };
  auto STAGE_H0 = [&](int tt, int buf) {
    const ushort_t *Ab, *Bb; int k0; SRC(tt, Ab, Bb, k0);
    GLL(Ab + offA[0] + k0, &lsA[buf][(4 * w + 0) * 512]);
    GLL(Ab + offA[1] + k0, &lsA[buf][(4 * w + 1) * 512]);
    GLL(Bb + offB[0] + k0, &lsB[buf][(2 * w + 0) * 512]);
  };
  auto STAGE_H1 = [&](int tt, int buf) {
    const ushort_t *Ab, *Bb; int k0; SRC(tt, Ab, Bb, k0);
    GLL(Ab + offA[2] + k0, &lsA[buf][(4 * w + 2) * 512]);
    GLL(Ab + offA[3] + k0, &lsA[buf][(4 * w + 3) * 512]);
    GLL(Bb + offB[1] + k0, &lsB[buf][(2 * w + 1) * 512]);
  };
  auto READF = [&](bf16x8 (&av)[4], bf16x8 (&bv)[4], int cur, int kh) {
#pragma unroll
    for (int i = 0; i < 4; ++i) av[i] = *(const bf16x8*)(&lsA[cur][aoff[kh][i]]);
#pragma unroll
    for (int j = 0; j < 4; ++j) bv[j] = *(const bf16x8*)(&lsB[cur][boff[kh][j]]);
  };
  auto DOMFMA = [&](bf16x8 (&av)[4], bf16x8 (&bv)[4]) {
    __builtin_amdgcn_s_setprio(1);
#pragma unroll
    for (int i = 0; i < 4; ++i)
#pragma unroll
      for (int j = 0; j < 4; ++j)
        acc[i][j] = __builtin_amdgcn_mfma_f32_16x16x32_bf16(av[i], bv[j], acc[i][j], 0, 0, 0);
    __builtin_amdgcn_s_setprio(0);
  };

  bf16x8 avA[4], bvA[4], avB[4], bvB[4];

  STAGE_H0(0, 0); STAGE_H1(0, 0);
  STAGE_H0(1, 1); STAGE_H1(1, 1);
  asm volatile("s_waitcnt vmcnt(6)" ::: "memory");
  __builtin_amdgcn_s_barrier();
  READF(avA, bvA, 0, 0);

#pragma unroll 1
  for (int t = 0; t < NT; ++t) {
    const int cur = t % 3, nb = (t + 2) % 3, nxt = (t + 1) % 3;
    READF(avB, bvB, cur, 1);
    if (t + 2 < NT) STAGE_H0(t + 2, nb);
    DOMFMA(avA, bvA);
    if (t + 1 < NT) {
      if (t + 2 < NT) { asm volatile("s_waitcnt vmcnt(3)\n\ts_barrier" ::: "memory"); }
      else            { asm volatile("s_waitcnt vmcnt(0)\n\ts_barrier" ::: "memory"); }
      READF(avA, bvA, nxt, 0);
      if (t + 2 < NT) STAGE_H1(t + 2, nb);
    }
    DOMFMA(avB, bvB);
  }

  const int lr = (lane >> 4) * 4, lc = lane & 15;
  const int rbase = m0 + wr * 64, cbase = n0 + wc * 64;
  if constexpr (MODE == 0) {
    float* Out = (float*)OutV;
#pragma unroll
    for (int j = 0; j < 4; ++j) {
      const int col = cbase + j * 16 + lc;
      const float qbn = qbias[col];
      const float cb = vbias[b * DM + col] + bo[col];
#pragma unroll
      for (int i = 0; i < 4; ++i)
#pragma unroll
        for (int r = 0; r < 4; ++r) {
          const int row = rbase + i * 16 + lr + r;
          Out[(size_t)row * DM + col] = acc[i][j][r] + gqw[row & (SEQ - 1)] * qbn + cb;
        }
    }
  } else {
    ushort_t* Out = (ushort_t*)OutV + (size_t)blockIdx.z * (DM * DM);
#pragma unroll
    for (int j = 0; j < 4; ++j) {
      const int col = cbase + j * 16 + lc;
#pragma unroll
      for (int i = 0; i < 4; ++i)
#pragma unroll
        for (int r = 0; r < 4; ++r) {
          const int row = rbase + i * 16 + lr + r;
          Out[(size_t)row * DM + col] = f2bf(acc[i][j][r]);
        }
    }
  }
}

// ---------------------------------------------------------------------------
extern "C" void kernel_launch(void* const* d_in, const int* in_sizes, int n_in,
                              void* d_out, int out_size, void* d_ws, size_t ws_size,
                              hipStream_t stream) {
  // input order: v k q mask wq bq wk bk wv bv gqw gkw wo bo
  const float* v   = (const float*)d_in[0];
  const float* k   = (const float*)d_in[1];
  const float* q   = (const float*)d_in[2];
  const float* wq  = (const float*)d_in[4];
  const float* bq  = (const float*)d_in[5];
  const float* wk  = (const float*)d_in[6];
  const float* bk  = (const float*)d_in[7];
  const float* wv  = (const float*)d_in[8];
  const float* bv  = (const float*)d_in[9];
  const float* gqw = (const float*)d_in[10];
  const float* gkw = (const float*)d_in[11];
  const float* wo  = (const float*)d_in[12];
  const float* bo  = (const float*)d_in[13];
  float* out = (float*)d_out;
  float* wsf = (float*)d_ws;

  // fp32 scratch: [qr kr qacc kacc | G | qbias | vbias]
  float* qr    = wsf + 0;
  float* kr    = wsf + 4096;
  float* qacc  = wsf + 8192;
  float* kacc  = wsf + 12288;
  float* G     = wsf + 16384;   // 2 floats
  float* qbias = wsf + 16640;   // 1024
  float* vbias = wsf + 17664;   // 4096 (ends at 21760)
  // bf16 scratch at byte offset 128 KiB
  ushort_t* b16  = (ushort_t*)((char*)d_ws + (1 << 17));
  ushort_t* qb   = b16;                                 // 16MB gqw-scaled
  ushort_t* vb   = qb + (size_t)M_TOT * DM;             // 16MB
  ushort_t* wqB  = vb + (size_t)M_TOT * DM;             // 2MB
  ushort_t* wvB  = wqB + (size_t)DM * DM;               // 2MB
  ushort_t* woT  = wvB + (size_t)DM * DM;               // 2MB [N][K]
  ushort_t* WqoT = woT + (size_t)DM * DM;               // 2MB
  ushort_t* WvbT = WqoT + (size_t)DM * DM;              // 8MB [4][N][K]
  // dead d_out space hosts transient buffers (consumed before k_pipe<0> writes):
  ushort_t* wogT = (ushort_t*)out;       // [0, 8MB)
  float* pq = out + (1 << 22);           // [16, 18MB): 128 slots x 4 x 1024 f32
  float* pk = pq + (1 << 20);            // [20, 22MB)

  hipMemsetAsync(d_ws, 0, 21760 * sizeof(float), stream);

  // merged: weight preps + data reductions/conversions (independent work)
  k_prep_reduce<<<2560, 256, 0, stream>>>(q, k, v, gqw, gkw, wq, wv, wo,
                                          pq, pk, G, qb, vb, wqB, wvB, woT);

  // fold partials -> qr/kr
  k_rsum<<<dim3(BATCH, DM / 256, 4), 256, 0, stream>>>(pq, pk, qr, kr);

  // global-vector GEMV partials
  k_gpart<<<dim3(DM / 256, DM / 32), 256, 0, stream>>>(wq, wk, qr, kr, qacc, kacc);

  // merged: composed-weight prep + bias (independent work; gk inline)
  k_wogbias<<<2176, 256, 0, stream>>>(woT, wo, qacc, kacc, bq, bk, bv, G,
                                      wogT, qbias, vbias);

  // small GEMMs (pipelined, BM=256, 160 blocks): z=0 WqoT, z>0 WvbT[z-1]
  k_pipe<1, 16><<<dim3(4, 8, 5), 512, 0, stream>>>(
      woT, wqB, wogT, wvB, nullptr, nullptr, nullptr, nullptr, WqoT);

  // the one big GEMM -> out
  k_pipe<0, 32><<<dim3(M_TOT / 256, DM / 128), 512, 0, stream>>>(
      qb, WqoT, vb, WvbT, gqw, qbias, vbias, bo, out);
}

// Round 23
// 115.993 us; speedup vs baseline: 1.0757x; 1.0070x over previous
//
#include <hip/hip_runtime.h>

#define DM 1024
#define BATCH 4
#define SEQ 2048
#define M_TOT (BATCH*SEQ)

typedef unsigned short ushort_t;
typedef __bf16 bf16x8 __attribute__((ext_vector_type(8)));
typedef float f32x4 __attribute__((ext_vector_type(4)));
typedef unsigned short u16x4 __attribute__((ext_vector_type(4)));
typedef unsigned short u16x8 __attribute__((ext_vector_type(8)));

__device__ __forceinline__ ushort_t f2bf(float f) {
  unsigned u = __builtin_bit_cast(unsigned, f);
  u = (u + 0x7fffu + ((u >> 16) & 1u)) >> 16;
  return (ushort_t)u;
}
__device__ __forceinline__ float bf2f(ushort_t h) {
  unsigned u = ((unsigned)h) << 16;
  return __builtin_bit_cast(float, u);
}

// async global->LDS, 16B per lane, wave-uniform LDS base + lane*16
#define GLL(gp, lp)                                                            \
  __builtin_amdgcn_global_load_lds(                                            \
      (const __attribute__((address_space(1))) unsigned int*)(const void*)(gp),\
      (__attribute__((address_space(3))) unsigned int*)(void*)(lp), 16, 0, 0)

// ---------------------------------------------------------------------------
// K1 (MERGED, independent work): 1D grid 3072.
// [0,1024):    k_reduce body, 8 rows/block (b = bid&3, sc = bid>>2, 0..255)
// [1024,2048): conv wq->wqB / wv->wvB   [2048,3072): transpose wo->woT
__global__ void k_prep_reduce(const float* __restrict__ q, const float* __restrict__ k,
                              const float* __restrict__ v,
                              const float* __restrict__ gqw, const float* __restrict__ gkw,
                              const float* __restrict__ wq, const float* __restrict__ wv,
                              const float* __restrict__ wo,
                              float* __restrict__ pq, float* __restrict__ pk,
                              float* __restrict__ G,
                              ushort_t* __restrict__ qb, ushort_t* __restrict__ vb,
                              ushort_t* __restrict__ wqB, ushort_t* __restrict__ wvB,
                              ushort_t* __restrict__ woT) {
  const int bid = blockIdx.x;
  if (bid < 1024) {
    const int b = bid & 3, sc = bid >> 2;   // sc: 0..255 (8-row chunks)
    const int d0 = threadIdx.x * 4;
    const int s0 = sc * 8;
    const size_t base = ((size_t)b * SEQ + s0) * DM + d0;
    float aq0 = 0.f, aq1 = 0.f, aq2 = 0.f, aq3 = 0.f;
    float ak0 = 0.f, ak1 = 0.f, ak2 = 0.f, ak3 = 0.f;
    float sgq = 0.f, sgk = 0.f;
#pragma unroll
    for (int i = 0; i < 8; ++i) {
      const float wq_ = gqw[s0 + i], wk_ = gkw[s0 + i];
      const size_t off = base + (size_t)i * DM;
      const float4 qv = *(const float4*)(q + off);
      const float4 kv = *(const float4*)(k + off);
      const float4 vv = *(const float4*)(v + off);
      aq0 += wq_ * qv.x; aq1 += wq_ * qv.y; aq2 += wq_ * qv.z; aq3 += wq_ * qv.w;
      ak0 += wk_ * kv.x; ak1 += wk_ * kv.y; ak2 += wk_ * kv.z; ak3 += wk_ * kv.w;
      u16x4 oq, ov;
      oq[0] = f2bf(wq_ * qv.x); oq[1] = f2bf(wq_ * qv.y);
      oq[2] = f2bf(wq_ * qv.z); oq[3] = f2bf(wq_ * qv.w);
      ov[0] = f2bf(vv.x); ov[1] = f2bf(vv.y); ov[2] = f2bf(vv.z); ov[3] = f2bf(vv.w);
      *(u16x4*)(qb + off) = oq;
      *(u16x4*)(vb + off) = ov;
      sgq += wq_; sgk += wk_;
    }
    const size_t po = ((size_t)(sc * BATCH + b) << 10) + d0;
    *(float4*)(pq + po) = make_float4(aq0, aq1, aq2, aq3);
    *(float4*)(pk + po) = make_float4(ak0, ak1, ak2, ak3);
    if (b == 0 && threadIdx.x == 0) {
      atomicAdd(&G[0], sgq);
      atomicAdd(&G[1], sgk);
    }
  } else if (bid < 2048) {
    const float* x = bid < 1536 ? wq : wv;
    ushort_t* y = bid < 1536 ? wqB : wvB;
    size_t i = (size_t)((bid - 1024) & 511) * 256 + threadIdx.x;
    const float4* p = (const float4*)x + i * 2;
    float4 a = p[0], bb = p[1];
    u16x8 o;
    o[0] = f2bf(a.x); o[1] = f2bf(a.y); o[2] = f2bf(a.z); o[3] = f2bf(a.w);
    o[4] = f2bf(bb.x); o[5] = f2bf(bb.y); o[6] = f2bf(bb.z); o[7] = f2bf(bb.w);
    *(u16x8*)(y + i * 8) = o;
  } else {
    __shared__ float ls[32][33];
    const int t = bid - 2048;
    const int bi = t >> 5, bj = t & 31;
#pragma unroll
    for (int p = 0; p < 4; ++p) {
      int e = threadIdx.x + p * 256;
      int r = e >> 5, c = e & 31;
      ls[r][c] = wo[(size_t)(bi * 32 + r) * DM + bj * 32 + c];
    }
    __syncthreads();
#pragma unroll
    for (int p = 0; p < 4; ++p) {
      int e = threadIdx.x + p * 256;
      int r = e >> 5, c = e & 31;
      woT[(size_t)(bj * 32 + r) * DM + bi * 32 + c] = f2bf(ls[c][r]);
    }
  }
}

// K1b: fold 256 partial slots into qr/kr. grid (4,4,8), 32K atomics.
__global__ void k_rsum(const float* __restrict__ pq, const float* __restrict__ pk,
                       float* __restrict__ qr, float* __restrict__ kr) {
  const int b = blockIdx.x;
  const int d = blockIdx.y * 256 + threadIdx.x;
  const int sg = blockIdx.z;
  float aq = 0.f, ak = 0.f;
#pragma unroll 4
  for (int s = sg * 32; s < sg * 32 + 32; ++s) {
    const size_t po = ((size_t)(s * BATCH + b) << 10) + d;
    aq += pq[po];
    ak += pk[po];
  }
  atomicAdd(&qr[b * DM + d], aq);
  atomicAdd(&kr[b * DM + d], ak);
}

// K2: partial GEMV over K-chunks (R19-verified)
__global__ void k_gpart(const float* __restrict__ wq, const float* __restrict__ wk,
                        const float* __restrict__ qr, const float* __restrict__ kr,
                        float* __restrict__ qacc, float* __restrict__ kacc) {
  const int d = blockIdx.x * 256 + threadIdx.x;
  const int k0 = blockIdx.y * 32;
  __shared__ float sq[4][32], sk[4][32];
  if (threadIdx.x < 128) {
    const int b = threadIdx.x >> 5, kk = threadIdx.x & 31;
    sq[b][kk] = qr[b * DM + k0 + kk];
    sk[b][kk] = kr[b * DM + k0 + kk];
  }
  __syncthreads();
  float aq[4] = {0.f, 0.f, 0.f, 0.f}, ak[4] = {0.f, 0.f, 0.f, 0.f};
#pragma unroll 8
  for (int kk = 0; kk < 32; ++kk) {
    const float wqv = wq[(size_t)(k0 + kk) * DM + d];
    const float wkv = wk[(size_t)(k0 + kk) * DM + d];
#pragma unroll
    for (int b = 0; b < 4; ++b) {
      aq[b] += sq[b][kk] * wqv;
      ak[b] += sk[b][kk] * wkv;
    }
  }
#pragma unroll
  for (int b = 0; b < 4; ++b) {
    atomicAdd(&qacc[b * DM + d], aq[b]);
    atomicAdd(&kacc[b * DM + d], ak[b]);
  }
}

// K4: merged wog + bias (independent work; 1D grid 2176, branch at 2048).
__global__ void k_wogbias(const ushort_t* __restrict__ woT, const float* __restrict__ wo,
                          const float* __restrict__ qacc, const float* __restrict__ kacc,
                          const float* __restrict__ bq, const float* __restrict__ bk,
                          const float* __restrict__ bv, const float* __restrict__ G,
                          ushort_t* __restrict__ wogT,
                          float* __restrict__ qbias, float* __restrict__ vbias) {
  const int bid = blockIdx.x;
  const float G0 = G[0], G1 = G[1];
  if (bid < 2048) {
    const size_t i = (size_t)bid * 256 + threadIdx.x;
    const size_t c = i * 8;
    const int j0 = (int)(c & (DM - 1));
    const int b = (int)(c >> 20);
    u16x8 wv8 = *(const u16x8*)(woT + (c & ((1u << 20) - 1)));
    const float4 qa0 = *(const float4*)(qacc + b * DM + j0);
    const float4 qa1 = *(const float4*)(qacc + b * DM + j0 + 4);
    const float4 ka0 = *(const float4*)(kacc + b * DM + j0);
    const float4 ka1 = *(const float4*)(kacc + b * DM + j0 + 4);
    const float4 bq0 = *(const float4*)(bq + j0);
    const float4 bq1 = *(const float4*)(bq + j0 + 4);
    const float4 bk0 = *(const float4*)(bk + j0);
    const float4 bk1 = *(const float4*)(bk + j0 + 4);
    float qa[8] = {qa0.x, qa0.y, qa0.z, qa0.w, qa1.x, qa1.y, qa1.z, qa1.w};
    float ka[8] = {ka0.x, ka0.y, ka0.z, ka0.w, ka1.x, ka1.y, ka1.z, ka1.w};
    float bqv[8] = {bq0.x, bq0.y, bq0.z, bq0.w, bq1.x, bq1.y, bq1.z, bq1.w};
    float bkv[8] = {bk0.x, bk0.y, bk0.z, bk0.w, bk1.x, bk1.y, bk1.z, bk1.w};
    u16x8 o;
#pragma unroll
    for (int j = 0; j < 8; ++j) {
      const float gk = (qa[j] + bqv[j] * G0) * (ka[j] + bkv[j] * G1);
      o[j] = f2bf(bf2f(wv8[j]) * gk);
    }
    *(u16x8*)(wogT + i * 8) = o;
  } else {
    const int t = bid - 2048;            // 0..127: (dchunk 0..3, kchunk 0..31)
    const int n = (t & 3) * 256 + threadIdx.x;
    const int k0 = (t >> 2) * 32;
    float aq = 0.f, av[4] = {0.f, 0.f, 0.f, 0.f};
    for (int kk = 0; kk < 32; ++kk) {
      const int j = k0 + kk;
      const float w = wo[(size_t)j * DM + n];
      aq += bq[j] * w;
      const float bw = bv[j] * w;
      const float bqj = bq[j] * G0, bkj = bk[j] * G1;
#pragma unroll
      for (int b = 0; b < 4; ++b) {
        const float gkv = (qacc[b * DM + j] + bqj) * (kacc[b * DM + j] + bkj);
        av[b] += bw * gkv;
      }
    }
    atomicAdd(&qbias[n], aq);
#pragma unroll
    for (int b = 0; b < 4; ++b) atomicAdd(&vbias[b * DM + n], av[b]);
  }
}

// ---------------------------------------------------------------------------
// K_PIPE: read-ahead pipelined GEMM (R18-verified). BM=256 BN=128, 8 waves
// 4x2 (wave-tile 64x64, acc 4x4), 3-buf LDS. Per K-tile: 2 phases, ds_read of
// next phase before MFMA of current, ONE counted vmcnt+barrier per tile.
// MODE 0 (NT=32): K_eff=2048; f32 epilogue. Grid (32,8).
// MODE 1 (NT=16): weight GEMMs z=0..4; bf16 epilogue. Grid (4,8,5).
template <int MODE, int NT>
__global__ __launch_bounds__(512, 1)
void k_pipe(const ushort_t* __restrict__ A0, const ushort_t* __restrict__ B0,
            const ushort_t* __restrict__ A1, const ushort_t* __restrict__ B1,
            const float* __restrict__ gqw, const float* __restrict__ qbias,
            const float* __restrict__ vbias, const float* __restrict__ bo,
            void* __restrict__ OutV) {
  __shared__ __align__(16) ushort_t lsA[3][256 * 64];  // 3 x 32 KB
  __shared__ __align__(16) ushort_t lsB[3][128 * 64];  // 3 x 16 KB
  const int tid = threadIdx.x;
  const int w = tid >> 6, lane = tid & 63;
  const int m0 = blockIdx.x * 256, n0 = blockIdx.y * 128;
  const int b = (MODE == 0) ? (m0 >> 11) : 0;
  const int wr = w >> 1, wc = w & 1;  // 4x2 wave grid, per-wave 64x64 out

  const ushort_t *Aq, *Bq, *Av = nullptr, *Bv = nullptr;
  if constexpr (MODE == 0) {
    Aq = A0; Bq = B0; Av = A1; Bv = B1 + (size_t)b * (DM * DM);
  } else {
    const int z = blockIdx.z;
    Aq = z ? A1 + (size_t)(z - 1) * (DM * DM) : A0;
    Bq = z ? B1 : B0;
  }

  const int subrow = lane >> 3;
  const int srcslot = (lane & 7) ^ subrow;
  size_t offA[4], offB[2];
#pragma unroll
  for (int p = 0; p < 4; ++p) {
    const int row = (4 * w + p) * 8 + subrow;           // 0..255
    offA[p] = (size_t)(m0 + row) * DM + srcslot * 8;
  }
#pragma unroll
  for (int p = 0; p < 2; ++p) {
    const int row = (2 * w + p) * 8 + subrow;           // 0..127
    offB[p] = (size_t)(n0 + row) * DM + srcslot * 8;
  }

  const int g = lane >> 4, l7 = lane & 7, l15 = lane & 15;
  int aoff[2][4], boff[2][4];
#pragma unroll
  for (int kh = 0; kh < 2; ++kh) {
#pragma unroll
    for (int i = 0; i < 4; ++i) {
      const int ra = wr * 64 + i * 16 + l15;
      aoff[kh][i] = ra * 64 + (((kh * 4 + g) ^ l7) * 8);
    }
#pragma unroll
    for (int j = 0; j < 4; ++j) {
      const int rb = wc * 64 + j * 16 + l15;
      boff[kh][j] = rb * 64 + (((kh * 4 + g) ^ l7) * 8);
    }
  }

  f32x4 acc[4][4];
#pragma unroll
  for (int i = 0; i < 4; ++i)
#pragma unroll
    for (int j = 0; j < 4; ++j) acc[i][j] = (f32x4){0.f, 0.f, 0.f, 0.f};

  auto SRC = [&](int tt, const ushort_t*& Ab, const ushort_t*& Bb, int& k0) {
    if (MODE == 0 && tt >= NT / 2) { Ab = Av; Bb = Bv; k0 = (tt - NT / 2) * 64; }
    else                           { Ab = Aq; Bb = Bq; k0 = tt * 64; }
  };
  auto STAGE_H0 = [&](int tt, int buf) {
    const ushort_t *Ab, *Bb; int k0; SRC(tt, Ab, Bb, k0);
    GLL(Ab + offA[0] + k0, &lsA[buf][(4 * w + 0) * 512]);
    GLL(Ab + offA[1] + k0, &lsA[buf][(4 * w + 1) * 512]);
    GLL(Bb + offB[0] + k0, &lsB[buf][(2 * w + 0) * 512]);
  };
  auto STAGE_H1 = [&](int tt, int buf) {
    const ushort_t *Ab, *Bb; int k0; SRC(tt, Ab, Bb, k0);
    GLL(Ab + offA[2] + k0, &lsA[buf][(4 * w + 2) * 512]);
    GLL(Ab + offA[3] + k0, &lsA[buf][(4 * w + 3) * 512]);
    GLL(Bb + offB[1] + k0, &lsB[buf][(2 * w + 1) * 512]);
  };
  auto READF = [&](bf16x8 (&av)[4], bf16x8 (&bv)[4], int cur, int kh) {
#pragma unroll
    for (int i = 0; i < 4; ++i) av[i] = *(const bf16x8*)(&lsA[cur][aoff[kh][i]]);
#pragma unroll
    for (int j = 0; j < 4; ++j) bv[j] = *(const bf16x8*)(&lsB[cur][boff[kh][j]]);
  };
  auto DOMFMA = [&](bf16x8 (&av)[4], bf16x8 (&bv)[4]) {
    __builtin_amdgcn_s_setprio(1);
#pragma unroll
    for (int i = 0; i < 4; ++i)
#pragma unroll
      for (int j = 0; j < 4; ++j)
        acc[i][j] = __builtin_amdgcn_mfma_f32_16x16x32_bf16(av[i], bv[j], acc[i][j], 0, 0, 0);
    __builtin_amdgcn_s_setprio(0);
  };

  bf16x8 avA[4], bvA[4], avB[4], bvB[4];

  STAGE_H0(0, 0); STAGE_H1(0, 0);
  STAGE_H0(1, 1); STAGE_H1(1, 1);
  asm volatile("s_waitcnt vmcnt(6)" ::: "memory");
  __builtin_amdgcn_s_barrier();
  READF(avA, bvA, 0, 0);

#pragma unroll 1
  for (int t = 0; t < NT; ++t) {
    const int cur = t % 3, nb = (t + 2) % 3, nxt = (t + 1) % 3;
    READF(avB, bvB, cur, 1);
    if (t + 2 < NT) STAGE_H0(t + 2, nb);
    DOMFMA(avA, bvA);
    if (t + 1 < NT) {
      if (t + 2 < NT) { asm volatile("s_waitcnt vmcnt(3)\n\ts_barrier" ::: "memory"); }
      else            { asm volatile("s_waitcnt vmcnt(0)\n\ts_barrier" ::: "memory"); }
      READF(avA, bvA, nxt, 0);
      if (t + 2 < NT) STAGE_H1(t + 2, nb);
    }
    DOMFMA(avB, bvB);
  }

  const int lr = (lane >> 4) * 4, lc = lane & 15;
  const int rbase = m0 + wr * 64, cbase = n0 + wc * 64;
  if constexpr (MODE == 0) {
    float* Out = (float*)OutV;
#pragma unroll
    for (int j = 0; j < 4; ++j) {
      const int col = cbase + j * 16 + lc;
      const float qbn = qbias[col];
      const float cb = vbias[b * DM + col] + bo[col];
#pragma unroll
      for (int i = 0; i < 4; ++i)
#pragma unroll
        for (int r = 0; r < 4; ++r) {
          const int row = rbase + i * 16 + lr + r;
          Out[(size_t)row * DM + col] = acc[i][j][r] + gqw[row & (SEQ - 1)] * qbn + cb;
        }
    }
  } else {
    ushort_t* Out = (ushort_t*)OutV + (size_t)blockIdx.z * (DM * DM);
#pragma unroll
    for (int j = 0; j < 4; ++j) {
      const int col = cbase + j * 16 + lc;
#pragma unroll
      for (int i = 0; i < 4; ++i)
#pragma unroll
        for (int r = 0; r < 4; ++r) {
          const int row = rbase + i * 16 + lr + r;
          Out[(size_t)row * DM + col] = f2bf(acc[i][j][r]);
        }
    }
  }
}

// ---------------------------------------------------------------------------
extern "C" void kernel_launch(void* const* d_in, const int* in_sizes, int n_in,
                              void* d_out, int out_size, void* d_ws, size_t ws_size,
                              hipStream_t stream) {
  // input order: v k q mask wq bq wk bk wv bv gqw gkw wo bo
  const float* v   = (const float*)d_in[0];
  const float* k   = (const float*)d_in[1];
  const float* q   = (const float*)d_in[2];
  const float* wq  = (const float*)d_in[4];
  const float* bq  = (const float*)d_in[5];
  const float* wk  = (const float*)d_in[6];
  const float* bk  = (const float*)d_in[7];
  const float* wv  = (const float*)d_in[8];
  const float* bv  = (const float*)d_in[9];
  const float* gqw = (const float*)d_in[10];
  const float* gkw = (const float*)d_in[11];
  const float* wo  = (const float*)d_in[12];
  const float* bo  = (const float*)d_in[13];
  float* out = (float*)d_out;
  float* wsf = (float*)d_ws;

  // fp32 scratch: [qr kr qacc kacc | G | qbias | vbias]
  float* qr    = wsf + 0;
  float* kr    = wsf + 4096;
  float* qacc  = wsf + 8192;
  float* kacc  = wsf + 12288;
  float* G     = wsf + 16384;   // 2 floats
  float* qbias = wsf + 16640;   // 1024
  float* vbias = wsf + 17664;   // 4096 (ends at 21760)
  // bf16 scratch at byte offset 128 KiB
  ushort_t* b16  = (ushort_t*)((char*)d_ws + (1 << 17));
  ushort_t* qb   = b16;                                 // 16MB gqw-scaled
  ushort_t* vb   = qb + (size_t)M_TOT * DM;             // 16MB
  ushort_t* wqB  = vb + (size_t)M_TOT * DM;             // 2MB
  ushort_t* wvB  = wqB + (size_t)DM * DM;               // 2MB
  ushort_t* woT  = wvB + (size_t)DM * DM;               // 2MB [N][K]
  ushort_t* WqoT = woT + (size_t)DM * DM;               // 2MB
  ushort_t* WvbT = WqoT + (size_t)DM * DM;              // 8MB [4][N][K]
  // dead d_out space hosts transient buffers (consumed before k_pipe<0> writes):
  ushort_t* wogT = (ushort_t*)out;       // [0, 8MB)
  float* pq = out + (1 << 22);           // [16, 20MB): 256 slots x 4 x 1024 f32
  float* pk = pq + (1 << 20);            // [20, 24MB)

  hipMemsetAsync(d_ws, 0, 21760 * sizeof(float), stream);

  // merged: weight preps + data reductions/conversions (independent work;
  // reduce now 8 rows/block = 1024 streaming blocks for 2x MLP)
  k_prep_reduce<<<3072, 256, 0, stream>>>(q, k, v, gqw, gkw, wq, wv, wo,
                                          pq, pk, G, qb, vb, wqB, wvB, woT);

  // fold 256 partial slots -> qr/kr
  k_rsum<<<dim3(BATCH, DM / 256, 8), 256, 0, stream>>>(pq, pk, qr, kr);

  // global-vector GEMV partials
  k_gpart<<<dim3(DM / 256, DM / 32), 256, 0, stream>>>(wq, wk, qr, kr, qacc, kacc);

  // merged: composed-weight prep + bias (independent work; gk inline)
  k_wogbias<<<2176, 256, 0, stream>>>(woT, wo, qacc, kacc, bq, bk, bv, G,
                                      wogT, qbias, vbias);

  // small GEMMs (pipelined, BM=256, 160 blocks): z=0 WqoT, z>0 WvbT[z-1]
  k_pipe<1, 16><<<dim3(4, 8, 5), 512, 0, stream>>>(
      woT, wqB, wogT, wvB, nullptr, nullptr, nullptr, nullptr, WqoT);

  // the one big GEMM -> out
  k_pipe<0, 32><<<dim3(M_TOT / 256, DM / 128), 512, 0, stream>>>(
      qb, WqoT, vb, WvbT, gqw, qbias, vbias, bo, out);
}

// Round 24
// 115.687 us; speedup vs baseline: 1.0785x; 1.0026x over previous
//
#include <hip/hip_runtime.h>

#define DM 1024
#define BATCH 4
#define SEQ 2048
#define M_TOT (BATCH*SEQ)

typedef unsigned short ushort_t;
typedef __bf16 bf16x8 __attribute__((ext_vector_type(8)));
typedef float f32x4 __attribute__((ext_vector_type(4)));
typedef unsigned short u16x4 __attribute__((ext_vector_type(4)));
typedef unsigned short u16x8 __attribute__((ext_vector_type(8)));

__device__ __forceinline__ ushort_t f2bf(float f) {
  unsigned u = __builtin_bit_cast(unsigned, f);
  u = (u + 0x7fffu + ((u >> 16) & 1u)) >> 16;
  return (ushort_t)u;
}
__device__ __forceinline__ float bf2f(ushort_t h) {
  unsigned u = ((unsigned)h) << 16;
  return __builtin_bit_cast(float, u);
}

// async global->LDS, 16B per lane, wave-uniform LDS base + lane*16
#define GLL(gp, lp)                                                            \
  __builtin_amdgcn_global_load_lds(                                            \
      (const __attribute__((address_space(1))) unsigned int*)(const void*)(gp),\
      (__attribute__((address_space(3))) unsigned int*)(void*)(lp), 16, 0, 0)

// ---------------------------------------------------------------------------
// K1 (STREAM-SPLIT): 1D grid 5120; each block touches ONE bulk stream.
// [0,1024):     q-blocks: read q, write qb = bf16(gqw*q), pq partials, G0
// [1024,2048):  k-blocks: read k, pk partials, G1 (no bulk write)
// [2048,3072):  v-blocks: read v, write vb = bf16(v)
// [3072,4096):  conv wq->wqB / wv->wvB
// [4096,5120):  transpose-convert wo->woT
__global__ void k_prep_reduce(const float* __restrict__ q, const float* __restrict__ k,
                              const float* __restrict__ v,
                              const float* __restrict__ gqw, const float* __restrict__ gkw,
                              const float* __restrict__ wq, const float* __restrict__ wv,
                              const float* __restrict__ wo,
                              float* __restrict__ pq, float* __restrict__ pk,
                              float* __restrict__ G,
                              ushort_t* __restrict__ qb, ushort_t* __restrict__ vb,
                              ushort_t* __restrict__ wqB, ushort_t* __restrict__ wvB,
                              ushort_t* __restrict__ woT) {
  const int bid = blockIdx.x;
  if (bid < 1024) {
    // ---- q stream: read q, write qb, accumulate pq ----
    const int b = bid & 3, sc = bid >> 2;   // sc: 0..255 (8-row chunks)
    const int d0 = threadIdx.x * 4;
    const int s0 = sc * 8;
    const size_t base = ((size_t)b * SEQ + s0) * DM + d0;
    float a0 = 0.f, a1 = 0.f, a2 = 0.f, a3 = 0.f, sg = 0.f;
#pragma unroll
    for (int i = 0; i < 8; ++i) {
      const float w_ = gqw[s0 + i];
      const size_t off = base + (size_t)i * DM;
      const float4 x = *(const float4*)(q + off);
      a0 += w_ * x.x; a1 += w_ * x.y; a2 += w_ * x.z; a3 += w_ * x.w;
      u16x4 o;
      o[0] = f2bf(w_ * x.x); o[1] = f2bf(w_ * x.y);
      o[2] = f2bf(w_ * x.z); o[3] = f2bf(w_ * x.w);
      *(u16x4*)(qb + off) = o;
      sg += w_;
    }
    const size_t po = ((size_t)(sc * BATCH + b) << 10) + d0;
    *(float4*)(pq + po) = make_float4(a0, a1, a2, a3);
    if (b == 0 && threadIdx.x == 0) atomicAdd(&G[0], sg);
  } else if (bid < 2048) {
    // ---- k stream: read k, accumulate pk (no bulk write) ----
    const int t = bid - 1024;
    const int b = t & 3, sc = t >> 2;
    const int d0 = threadIdx.x * 4;
    const int s0 = sc * 8;
    const size_t base = ((size_t)b * SEQ + s0) * DM + d0;
    float a0 = 0.f, a1 = 0.f, a2 = 0.f, a3 = 0.f, sg = 0.f;
#pragma unroll
    for (int i = 0; i < 8; ++i) {
      const float w_ = gkw[s0 + i];
      const size_t off = base + (size_t)i * DM;
      const float4 x = *(const float4*)(k + off);
      a0 += w_ * x.x; a1 += w_ * x.y; a2 += w_ * x.z; a3 += w_ * x.w;
      sg += w_;
    }
    const size_t po = ((size_t)(sc * BATCH + b) << 10) + d0;
    *(float4*)(pk + po) = make_float4(a0, a1, a2, a3);
    if (b == 0 && threadIdx.x == 0) atomicAdd(&G[1], sg);
  } else if (bid < 3072) {
    // ---- v stream: read v, write vb ----
    const int t = bid - 2048;
    const int b = t & 3, sc = t >> 2;
    const int d0 = threadIdx.x * 4;
    const int s0 = sc * 8;
    const size_t base = ((size_t)b * SEQ + s0) * DM + d0;
#pragma unroll
    for (int i = 0; i < 8; ++i) {
      const size_t off = base + (size_t)i * DM;
      const float4 x = *(const float4*)(v + off);
      u16x4 o;
      o[0] = f2bf(x.x); o[1] = f2bf(x.y); o[2] = f2bf(x.z); o[3] = f2bf(x.w);
      *(u16x4*)(vb + off) = o;
    }
  } else if (bid < 4096) {
    const float* x = bid < 3584 ? wq : wv;
    ushort_t* y = bid < 3584 ? wqB : wvB;
    size_t i = (size_t)((bid - 3072) & 511) * 256 + threadIdx.x;
    const float4* p = (const float4*)x + i * 2;
    float4 a = p[0], bb = p[1];
    u16x8 o;
    o[0] = f2bf(a.x); o[1] = f2bf(a.y); o[2] = f2bf(a.z); o[3] = f2bf(a.w);
    o[4] = f2bf(bb.x); o[5] = f2bf(bb.y); o[6] = f2bf(bb.z); o[7] = f2bf(bb.w);
    *(u16x8*)(y + i * 8) = o;
  } else {
    __shared__ float ls[32][33];
    const int t = bid - 4096;
    const int bi = t >> 5, bj = t & 31;
#pragma unroll
    for (int p = 0; p < 4; ++p) {
      int e = threadIdx.x + p * 256;
      int r = e >> 5, c = e & 31;
      ls[r][c] = wo[(size_t)(bi * 32 + r) * DM + bj * 32 + c];
    }
    __syncthreads();
#pragma unroll
    for (int p = 0; p < 4; ++p) {
      int e = threadIdx.x + p * 256;
      int r = e >> 5, c = e & 31;
      woT[(size_t)(bj * 32 + r) * DM + bi * 32 + c] = f2bf(ls[c][r]);
    }
  }
}

// K1b: fold 256 partial slots into qr/kr. grid (4,4,8), 32K atomics.
__global__ void k_rsum(const float* __restrict__ pq, const float* __restrict__ pk,
                       float* __restrict__ qr, float* __restrict__ kr) {
  const int b = blockIdx.x;
  const int d = blockIdx.y * 256 + threadIdx.x;
  const int sg = blockIdx.z;
  float aq = 0.f, ak = 0.f;
#pragma unroll 4
  for (int s = sg * 32; s < sg * 32 + 32; ++s) {
    const size_t po = ((size_t)(s * BATCH + b) << 10) + d;
    aq += pq[po];
    ak += pk[po];
  }
  atomicAdd(&qr[b * DM + d], aq);
  atomicAdd(&kr[b * DM + d], ak);
}

// K2: partial GEMV over K-chunks (R19-verified)
__global__ void k_gpart(const float* __restrict__ wq, const float* __restrict__ wk,
                        const float* __restrict__ qr, const float* __restrict__ kr,
                        float* __restrict__ qacc, float* __restrict__ kacc) {
  const int d = blockIdx.x * 256 + threadIdx.x;
  const int k0 = blockIdx.y * 32;
  __shared__ float sq[4][32], sk[4][32];
  if (threadIdx.x < 128) {
    const int b = threadIdx.x >> 5, kk = threadIdx.x & 31;
    sq[b][kk] = qr[b * DM + k0 + kk];
    sk[b][kk] = kr[b * DM + k0 + kk];
  }
  __syncthreads();
  float aq[4] = {0.f, 0.f, 0.f, 0.f}, ak[4] = {0.f, 0.f, 0.f, 0.f};
#pragma unroll 8
  for (int kk = 0; kk < 32; ++kk) {
    const float wqv = wq[(size_t)(k0 + kk) * DM + d];
    const float wkv = wk[(size_t)(k0 + kk) * DM + d];
#pragma unroll
    for (int b = 0; b < 4; ++b) {
      aq[b] += sq[b][kk] * wqv;
      ak[b] += sk[b][kk] * wkv;
    }
  }
#pragma unroll
  for (int b = 0; b < 4; ++b) {
    atomicAdd(&qacc[b * DM + d], aq[b]);
    atomicAdd(&kacc[b * DM + d], ak[b]);
  }
}

// K4: merged wog + bias (independent work; 1D grid 2176, branch at 2048).
__global__ void k_wogbias(const ushort_t* __restrict__ woT, const float* __restrict__ wo,
                          const float* __restrict__ qacc, const float* __restrict__ kacc,
                          const float* __restrict__ bq, const float* __restrict__ bk,
                          const float* __restrict__ bv, const float* __restrict__ G,
                          ushort_t* __restrict__ wogT,
                          float* __restrict__ qbias, float* __restrict__ vbias) {
  const int bid = blockIdx.x;
  const float G0 = G[0], G1 = G[1];
  if (bid < 2048) {
    const size_t i = (size_t)bid * 256 + threadIdx.x;
    const size_t c = i * 8;
    const int j0 = (int)(c & (DM - 1));
    const int b = (int)(c >> 20);
    u16x8 wv8 = *(const u16x8*)(woT + (c & ((1u << 20) - 1)));
    const float4 qa0 = *(const float4*)(qacc + b * DM + j0);
    const float4 qa1 = *(const float4*)(qacc + b * DM + j0 + 4);
    const float4 ka0 = *(const float4*)(kacc + b * DM + j0);
    const float4 ka1 = *(const float4*)(kacc + b * DM + j0 + 4);
    const float4 bq0 = *(const float4*)(bq + j0);
    const float4 bq1 = *(const float4*)(bq + j0 + 4);
    const float4 bk0 = *(const float4*)(bk + j0);
    const float4 bk1 = *(const float4*)(bk + j0 + 4);
    float qa[8] = {qa0.x, qa0.y, qa0.z, qa0.w, qa1.x, qa1.y, qa1.z, qa1.w};
    float ka[8] = {ka0.x, ka0.y, ka0.z, ka0.w, ka1.x, ka1.y, ka1.z, ka1.w};
    float bqv[8] = {bq0.x, bq0.y, bq0.z, bq0.w, bq1.x, bq1.y, bq1.z, bq1.w};
    float bkv[8] = {bk0.x, bk0.y, bk0.z, bk0.w, bk1.x, bk1.y, bk1.z, bk1.w};
    u16x8 o;
#pragma unroll
    for (int j = 0; j < 8; ++j) {
      const float gk = (qa[j] + bqv[j] * G0) * (ka[j] + bkv[j] * G1);
      o[j] = f2bf(bf2f(wv8[j]) * gk);
    }
    *(u16x8*)(wogT + i * 8) = o;
  } else {
    const int t = bid - 2048;            // 0..127: (dchunk 0..3, kchunk 0..31)
    const int n = (t & 3) * 256 + threadIdx.x;
    const int k0 = (t >> 2) * 32;
    float aq = 0.f, av[4] = {0.f, 0.f, 0.f, 0.f};
    for (int kk = 0; kk < 32; ++kk) {
      const int j = k0 + kk;
      const float w = wo[(size_t)j * DM + n];
      aq += bq[j] * w;
      const float bw = bv[j] * w;
      const float bqj = bq[j] * G0, bkj = bk[j] * G1;
#pragma unroll
      for (int b = 0; b < 4; ++b) {
        const float gkv = (qacc[b * DM + j] + bqj) * (kacc[b * DM + j] + bkj);
        av[b] += bw * gkv;
      }
    }
    atomicAdd(&qbias[n], aq);
#pragma unroll
    for (int b = 0; b < 4; ++b) atomicAdd(&vbias[b * DM + n], av[b]);
  }
}

// ---------------------------------------------------------------------------
// K_PIPE: read-ahead pipelined GEMM (R18-verified). BM=256 BN=128, 8 waves
// 4x2 (wave-tile 64x64, acc 4x4), 3-buf LDS. Per K-tile: 2 phases, ds_read of
// next phase before MFMA of current, ONE counted vmcnt+barrier per tile.
// MODE 0 (NT=32): K_eff=2048; f32 epilogue. Grid (32,8).
// MODE 1 (NT=16): weight GEMMs z=0..4; bf16 epilogue. Grid (4,8,5).
template <int MODE, int NT>
__global__ __launch_bounds__(512, 1)
void k_pipe(const ushort_t* __restrict__ A0, const ushort_t* __restrict__ B0,
            const ushort_t* __restrict__ A1, const ushort_t* __restrict__ B1,
            const float* __restrict__ gqw, const float* __restrict__ qbias,
            const float* __restrict__ vbias, const float* __restrict__ bo,
            void* __restrict__ OutV) {
  __shared__ __align__(16) ushort_t lsA[3][256 * 64];  // 3 x 32 KB
  __shared__ __align__(16) ushort_t lsB[3][128 * 64];  // 3 x 16 KB
  const int tid = threadIdx.x;
  const int w = tid >> 6, lane = tid & 63;
  const int m0 = blockIdx.x * 256, n0 = blockIdx.y * 128;
  const int b = (MODE == 0) ? (m0 >> 11) : 0;
  const int wr = w >> 1, wc = w & 1;  // 4x2 wave grid, per-wave 64x64 out

  const ushort_t *Aq, *Bq, *Av = nullptr, *Bv = nullptr;
  if constexpr (MODE == 0) {
    Aq = A0; Bq = B0; Av = A1; Bv = B1 + (size_t)b * (DM * DM);
  } else {
    const int z = blockIdx.z;
    Aq = z ? A1 + (size_t)(z - 1) * (DM * DM) : A0;
    Bq = z ? B1 : B0;
  }

  const int subrow = lane >> 3;
  const int srcslot = (lane & 7) ^ subrow;
  size_t offA[4], offB[2];
#pragma unroll
  for (int p = 0; p < 4; ++p) {
    const int row = (4 * w + p) * 8 + subrow;           // 0..255
    offA[p] = (size_t)(m0 + row) * DM + srcslot * 8;
  }
#pragma unroll
  for (int p = 0; p < 2; ++p) {
    const int row = (2 * w + p) * 8 + subrow;           // 0..127
    offB[p] = (size_t)(n0 + row) * DM + srcslot * 8;
  }

  const int g = lane >> 4, l7 = lane & 7, l15 = lane & 15;
  int aoff[2][4], boff[2][4];
#pragma unroll
  for (int kh = 0; kh < 2; ++kh) {
#pragma unroll
    for (int i = 0; i < 4; ++i) {
      const int ra = wr * 64 + i * 16 + l15;
      aoff[kh][i] = ra * 64 + (((kh * 4 + g) ^ l7) * 8);
    }
#pragma unroll
    for (int j = 0; j < 4; ++j) {
      const int rb = wc * 64 + j * 16 + l15;
      boff[kh][j] = rb * 64 + (((kh * 4 + g) ^ l7) * 8);
    }
  }

  f32x4 acc[4][4];
#pragma unroll
  for (int i = 0; i < 4; ++i)
#pragma unroll
    for (int j = 0; j < 4; ++j) acc[i][j] = (f32x4){0.f, 0.f, 0.f, 0.f};

  auto SRC = [&](int tt, const ushort_t*& Ab, const ushort_t*& Bb, int& k0) {
    if (MODE == 0 && tt >= NT / 2) { Ab = Av; Bb = Bv; k0 = (tt - NT / 2) * 64; }
    else                           { Ab = Aq; Bb = Bq; k0 = tt * 64; }
  };
  auto STAGE_H0 = [&](int tt, int buf) {
    const ushort_t *Ab, *Bb; int k0; SRC(tt, Ab, Bb, k0);
    GLL(Ab + offA[0] + k0, &lsA[buf][(4 * w + 0) * 512]);
    GLL(Ab + offA[1] + k0, &lsA[buf][(4 * w + 1) * 512]);
    GLL(Bb + offB[0] + k0, &lsB[buf][(2 * w + 0) * 512]);
  };
  auto STAGE_H1 = [&](int tt, int buf) {
    const ushort_t *Ab, *Bb; int k0; SRC(tt, Ab, Bb, k0);
    GLL(Ab + offA[2] + k0, &lsA[buf][(4 * w + 2) * 512]);
    GLL(Ab + offA[3] + k0, &lsA[buf][(4 * w + 3) * 512]);
    GLL(Bb + offB[1] + k0, &lsB[buf][(2 * w + 1) * 512]);
  };
  auto READF = [&](bf16x8 (&av)[4], bf16x8 (&bv)[4], int cur, int kh) {
#pragma unroll
    for (int i = 0; i < 4; ++i) av[i] = *(const bf16x8*)(&lsA[cur][aoff[kh][i]]);
#pragma unroll
    for (int j = 0; j < 4; ++j) bv[j] = *(const bf16x8*)(&lsB[cur][boff[kh][j]]);
  };
  auto DOMFMA = [&](bf16x8 (&av)[4], bf16x8 (&bv)[4]) {
    __builtin_amdgcn_s_setprio(1);
#pragma unroll
    for (int i = 0; i < 4; ++i)
#pragma unroll
      for (int j = 0; j < 4; ++j)
        acc[i][j] = __builtin_amdgcn_mfma_f32_16x16x32_bf16(av[i], bv[j], acc[i][j], 0, 0, 0);
    __builtin_amdgcn_s_setprio(0);
  };

  bf16x8 avA[4], bvA[4], avB[4], bvB[4];

  STAGE_H0(0, 0); STAGE_H1(0, 0);
  STAGE_H0(1, 1); STAGE_H1(1, 1);
  asm volatile("s_waitcnt vmcnt(6)" ::: "memory");
  __builtin_amdgcn_s_barrier();
  READF(avA, bvA, 0, 0);

#pragma unroll 1
  for (int t = 0; t < NT; ++t) {
    const int cur = t % 3, nb = (t + 2) % 3, nxt = (t + 1) % 3;
    READF(avB, bvB, cur, 1);
    if (t + 2 < NT) STAGE_H0(t + 2, nb);
    DOMFMA(avA, bvA);
    if (t + 1 < NT) {
      if (t + 2 < NT) { asm volatile("s_waitcnt vmcnt(3)\n\ts_barrier" ::: "memory"); }
      else            { asm volatile("s_waitcnt vmcnt(0)\n\ts_barrier" ::: "memory"); }
      READF(avA, bvA, nxt, 0);
      if (t + 2 < NT) STAGE_H1(t + 2, nb);
    }
    DOMFMA(avB, bvB);
  }

  const int lr = (lane >> 4) * 4, lc = lane & 15;
  const int rbase = m0 + wr * 64, cbase = n0 + wc * 64;
  if constexpr (MODE == 0) {
    float* Out = (float*)OutV;
#pragma unroll
    for (int j = 0; j < 4; ++j) {
      const int col = cbase + j * 16 + lc;
      const float qbn = qbias[col];
      const float cb = vbias[b * DM + col] + bo[col];
#pragma unroll
      for (int i = 0; i < 4; ++i)
#pragma unroll
        for (int r = 0; r < 4; ++r) {
          const int row = rbase + i * 16 + lr + r;
          Out[(size_t)row * DM + col] = acc[i][j][r] + gqw[row & (SEQ - 1)] * qbn + cb;
        }
    }
  } else {
    ushort_t* Out = (ushort_t*)OutV + (size_t)blockIdx.z * (DM * DM);
#pragma unroll
    for (int j = 0; j < 4; ++j) {
      const int col = cbase + j * 16 + lc;
#pragma unroll
      for (int i = 0; i < 4; ++i)
#pragma unroll
        for (int r = 0; r < 4; ++r) {
          const int row = rbase + i * 16 + lr + r;
          Out[(size_t)row * DM + col] = f2bf(acc[i][j][r]);
        }
    }
  }
}

// ---------------------------------------------------------------------------
extern "C" void kernel_launch(void* const* d_in, const int* in_sizes, int n_in,
                              void* d_out, int out_size, void* d_ws, size_t ws_size,
                              hipStream_t stream) {
  // input order: v k q mask wq bq wk bk wv bv gqw gkw wo bo
  const float* v   = (const float*)d_in[0];
  const float* k   = (const float*)d_in[1];
  const float* q   = (const float*)d_in[2];
  const float* wq  = (const float*)d_in[4];
  const float* bq  = (const float*)d_in[5];
  const float* wk  = (const float*)d_in[6];
  const float* bk  = (const float*)d_in[7];
  const float* wv  = (const float*)d_in[8];
  const float* bv  = (const float*)d_in[9];
  const float* gqw = (const float*)d_in[10];
  const float* gkw = (const float*)d_in[11];
  const float* wo  = (const float*)d_in[12];
  const float* bo  = (const float*)d_in[13];
  float* out = (float*)d_out;
  float* wsf = (float*)d_ws;

  // fp32 scratch: [qr kr qacc kacc | G | qbias | vbias]
  float* qr    = wsf + 0;
  float* kr    = wsf + 4096;
  float* qacc  = wsf + 8192;
  float* kacc  = wsf + 12288;
  float* G     = wsf + 16384;   // 2 floats
  float* qbias = wsf + 16640;   // 1024
  float* vbias = wsf + 17664;   // 4096 (ends at 21760)
  // bf16 scratch at byte offset 128 KiB
  ushort_t* b16  = (ushort_t*)((char*)d_ws + (1 << 17));
  ushort_t* qb   = b16;                                 // 16MB gqw-scaled
  ushort_t* vb   = qb + (size_t)M_TOT * DM;             // 16MB
  ushort_t* wqB  = vb + (size_t)M_TOT * DM;             // 2MB
  ushort_t* wvB  = wqB + (size_t)DM * DM;               // 2MB
  ushort_t* woT  = wvB + (size_t)DM * DM;               // 2MB [N][K]
  ushort_t* WqoT = woT + (size_t)DM * DM;               // 2MB
  ushort_t* WvbT = WqoT + (size_t)DM * DM;              // 8MB [4][N][K]
  // dead d_out space hosts transient buffers (consumed before k_pipe<0> writes):
  ushort_t* wogT = (ushort_t*)out;       // [0, 8MB)
  float* pq = out + (1 << 22);           // [16, 20MB): 256 slots x 4 x 1024 f32
  float* pk = pq + (1 << 20);            // [20, 24MB)

  hipMemsetAsync(d_ws, 0, 21760 * sizeof(float), stream);

  // stream-split: per-block single-stream access (q / k / v / conv / trans)
  k_prep_reduce<<<5120, 256, 0, stream>>>(q, k, v, gqw, gkw, wq, wv, wo,
                                          pq, pk, G, qb, vb, wqB, wvB, woT);

  // fold 256 partial slots -> qr/kr
  k_rsum<<<dim3(BATCH, DM / 256, 8), 256, 0, stream>>>(pq, pk, qr, kr);

  // global-vector GEMV partials
  k_gpart<<<dim3(DM / 256, DM / 32), 256, 0, stream>>>(wq, wk, qr, kr, qacc, kacc);

  // merged: composed-weight prep + bias (independent work; gk inline)
  k_wogbias<<<2176, 256, 0, stream>>>(woT, wo, qacc, kacc, bq, bk, bv, G,
                                      wogT, qbias, vbias);

  // small GEMMs (pipelined, BM=256, 160 blocks): z=0 WqoT, z>0 WvbT[z-1]
  k_pipe<1, 16><<<dim3(4, 8, 5), 512, 0, stream>>>(
      woT, wqB, wogT, wvB, nullptr, nullptr, nullptr, nullptr, WqoT);

  // the one big GEMM -> out
  k_pipe<0, 32><<<dim3(M_TOT / 256, DM / 128), 512, 0, stream>>>(
      qb, WqoT, vb, WvbT, gqw, qbias, vbias, bo, out);
}